// Round 8
// baseline (513.033 us; speedup 1.0000x reference)
//
#include <hip/hip_runtime.h>

// ---------------- common helpers ----------------
using bf16x8 = __attribute__((ext_vector_type(8))) short;
using bf16x4 = __attribute__((ext_vector_type(4))) short;
using f32x4  = __attribute__((ext_vector_type(4))) float;

#define DEV __device__ __forceinline__

DEV short f2bf(float x){
  unsigned u = __float_as_uint(x);
  u += 0x7fffu + ((u >> 16) & 1u);
  return (short)(u >> 16);
}
DEV float bf2f(short h){ return __uint_as_float(((unsigned)(unsigned short)h) << 16); }

#define MFMA16(a,b,c) __builtin_amdgcn_mfma_f32_16x16x32_bf16(a,b,c,0,0,0)

// async global->LDS, 16B per lane; LDS dest is wave-uniform base + lane*16
DEV void gl_lds16(const void* g, void* l){
  __builtin_amdgcn_global_load_lds(
      (const __attribute__((address_space(1))) unsigned*)g,
      (__attribute__((address_space(3))) unsigned*)l, 16, 0, 0);
}

// Problem constants: B=2 S=1024 D=768 H=12 HD=64 E=8 DF=3072 K=2, T=2048

// ---------------- transpose + fp32->bf16(hi/lo) convert, 64x64 tiles -------
__global__ void k_transpose(const float* __restrict__ src, long sbatch,
                            short* __restrict__ dhi, short* __restrict__ dlo, long dbatch,
                            int R, int C){
  __shared__ float tile[64][65];
  const float* s = src + (long)blockIdx.z * sbatch;
  int c0 = blockIdx.x * 64, r0 = blockIdx.y * 64;
  int tx = threadIdx.x & 15, ty = threadIdx.x >> 4;   // 16 col-quads x 16 rows
  #pragma unroll
  for (int i = 0; i < 4; i++){
    int r = ty + 16*i;
    float4 v = *(const float4*)&s[(long)(r0 + r) * C + c0 + tx*4];
    tile[r][tx*4+0] = v.x; tile[r][tx*4+1] = v.y;
    tile[r][tx*4+2] = v.z; tile[r][tx*4+3] = v.w;
  }
  __syncthreads();
  int rseg = (threadIdx.x & 7) * 8;                   // 8-row segment
  #pragma unroll
  for (int p = 0; p < 2; p++){
    int col = (threadIdx.x >> 3) + 32*p;              // 32 cols per pass
    short hv[8], lv[8];
    #pragma unroll
    for (int k = 0; k < 8; k++){
      float v = tile[rseg + k][col];
      hv[k] = f2bf(v);
      lv[k] = f2bf(v - bf2f(hv[k]));
    }
    long o = (long)blockIdx.z * dbatch + (long)(c0 + col) * R + r0 + rseg;
    *(bf16x8*)&dhi[o] = *(bf16x8*)&hv[0];
    if (dlo) *(bf16x8*)&dlo[o] = *(bf16x8*)&lv[0];
  }
}

// 4 square 768x768 weight transposes in ONE launch (z selects the matrix).
__global__ void k_transpose4(const float* __restrict__ s0, const float* __restrict__ s1,
                             const float* __restrict__ s2, const float* __restrict__ s3,
                             short* __restrict__ d0h, short* __restrict__ d0l,
                             short* __restrict__ d1h, short* __restrict__ d1l,
                             short* __restrict__ d2h, short* __restrict__ d2l,
                             short* __restrict__ d3h, short* __restrict__ d3l){
  int z = blockIdx.z;
  const float* s = (z==0) ? s0 : (z==1) ? s1 : (z==2) ? s2 : s3;
  short* dh = (z==0) ? d0h : (z==1) ? d1h : (z==2) ? d2h : d3h;
  short* dl = (z==0) ? d0l : (z==1) ? d1l : (z==2) ? d2l : d3l;
  __shared__ float tile[64][65];
  int c0 = blockIdx.x * 64, r0 = blockIdx.y * 64;
  int tx = threadIdx.x & 15, ty = threadIdx.x >> 4;
  #pragma unroll
  for (int i = 0; i < 4; i++){
    int r = ty + 16*i;
    float4 v = *(const float4*)&s[(long)(r0 + r) * 768 + c0 + tx*4];
    tile[r][tx*4+0] = v.x; tile[r][tx*4+1] = v.y;
    tile[r][tx*4+2] = v.z; tile[r][tx*4+3] = v.w;
  }
  __syncthreads();
  int rseg = (threadIdx.x & 7) * 8;
  #pragma unroll
  for (int p = 0; p < 2; p++){
    int col = (threadIdx.x >> 3) + 32*p;
    short hv[8], lv[8];
    #pragma unroll
    for (int k = 0; k < 8; k++){
      float v = tile[rseg + k][col];
      hv[k] = f2bf(v);
      lv[k] = f2bf(v - bf2f(hv[k]));
    }
    long o = (long)(c0 + col) * 768 + r0 + rseg;
    *(bf16x8*)&dh[o] = *(bf16x8*)&hv[0];
    *(bf16x8*)&dl[o] = *(bf16x8*)&lv[0];
  }
}

// ---------------- LayerNorm1: x -> xn1 hi/lo bf16 ----------------
__global__ void k_ln1(const float* __restrict__ x, const float* __restrict__ g,
                      const float* __restrict__ bb,
                      short* __restrict__ xh, short* __restrict__ xl){
  int t = blockIdx.x, tid = threadIdx.x;
  const float* xr = x + (long)t * 768;
  float v[3];
  #pragma unroll
  for (int j = 0; j < 3; j++) v[j] = xr[tid + 256*j];
  float s = v[0]+v[1]+v[2];
  float q = v[0]*v[0]+v[1]*v[1]+v[2]*v[2];
  #pragma unroll
  for (int o = 32; o > 0; o >>= 1){ s += __shfl_down(s,o,64); q += __shfl_down(q,o,64); }
  __shared__ float ss[4], qs[4];
  int w = tid >> 6;
  if ((tid & 63) == 0){ ss[w] = s; qs[w] = q; }
  __syncthreads();
  float St = ss[0]+ss[1]+ss[2]+ss[3], Qt = qs[0]+qs[1]+qs[2]+qs[3];
  float mean = St * (1.f/768.f);
  float var  = Qt * (1.f/768.f) - mean*mean;
  float inv  = 1.f / sqrtf(var + 1e-5f);
  #pragma unroll
  for (int j = 0; j < 3; j++){
    int d = tid + 256*j;
    float xn = (v[j]-mean)*inv*g[d] + bb[d];
    short hv = f2bf(xn);
    xh[(long)t*768 + d] = hv;
    xl[(long)t*768 + d] = f2bf(xn - bf2f(hv));
  }
}

// ---------------- split-bf16 GEMM: qkv = xn1 @ Wqkv -------------------------
// BM=64 BN=128: grid (32,18) = 576 blocks = 2.25/CU. LDS 48KB -> 3 blocks/CU.
__global__ __launch_bounds__(256,3) void k_qkv(
    const short* __restrict__ Ah, const short* __restrict__ Al,
    const short* __restrict__ Bh, const short* __restrict__ Bl,
    short* __restrict__ qh, short* __restrict__ ql,
    short* __restrict__ kh, short* __restrict__ kl,
    short* __restrict__ vh, short* __restrict__ vl){
  int M0 = blockIdx.x * 64, N0 = blockIdx.y * 128;
  __shared__ __align__(16) short lah[64*64], lal[64*64], lbh[128*64], lbl[128*64];
  int tid = threadIdx.x;
  int w = tid >> 6, lane = tid & 63, l15 = lane & 15, quad = lane >> 4;
  int mbase = (w & 1) * 32, nbase = (w >> 1) * 64;
  f32x4 acc[2][4];
  #pragma unroll
  for (int i = 0; i < 2; i++)
    #pragma unroll
    for (int j = 0; j < 4; j++) acc[i][j] = (f32x4){0.f,0.f,0.f,0.f};
  int rl = lane >> 3, pch = lane & 7;
  long gA[2], gB[4];
  #pragma unroll
  for (int j = 0; j < 2; j++){
    int r = w*16 + j*8 + rl;
    int c = pch ^ (r & 7);
    gA[j] = (long)(M0 + r)*768 + c*8;
  }
  #pragma unroll
  for (int j = 0; j < 4; j++){
    int r = w*32 + j*8 + rl;
    int c = pch ^ (r & 7);
    gB[j] = (long)(N0 + r)*768 + c*8;
  }
  for (int k0 = 0; k0 < 768; k0 += 64){
    #pragma unroll
    for (int j = 0; j < 2; j++){
      gl_lds16(Ah + gA[j] + k0, lah + w*1024 + j*512);
      gl_lds16(Al + gA[j] + k0, lal + w*1024 + j*512);
    }
    #pragma unroll
    for (int j = 0; j < 4; j++){
      gl_lds16(Bh + gB[j] + k0, lbh + w*2048 + j*512);
      gl_lds16(Bl + gB[j] + k0, lbl + w*2048 + j*512);
    }
    __syncthreads();
    #pragma unroll
    for (int kk = 0; kk < 2; kk++){
      int swq = ((kk*4 + quad) ^ (l15 & 7)) * 8;
      bf16x8 afh[2], afl[2];
      #pragma unroll
      for (int mt = 0; mt < 2; mt++){
        afh[mt] = *(const bf16x8*)&lah[(mbase+mt*16+l15)*64 + swq];
        afl[mt] = *(const bf16x8*)&lal[(mbase+mt*16+l15)*64 + swq];
      }
      #pragma unroll
      for (int nt = 0; nt < 4; nt++){
        bf16x8 bfh = *(const bf16x8*)&lbh[(nbase+nt*16+l15)*64 + swq];
        bf16x8 bfl = *(const bf16x8*)&lbl[(nbase+nt*16+l15)*64 + swq];
        #pragma unroll
        for (int mt = 0; mt < 2; mt++){
          acc[mt][nt] = MFMA16(afh[mt], bfh, acc[mt][nt]);
          acc[mt][nt] = MFMA16(afh[mt], bfl, acc[mt][nt]);
          acc[mt][nt] = MFMA16(afl[mt], bfh, acc[mt][nt]);
        }
      }
    }
    __syncthreads();
  }
  // epilogue: scatter into q[bh][s][hd], k[bh][s][hd], vT[bh][hd][s]
  // Q folds 1/sqrt(HD) * log2(e): softmax runs in log2 domain (exp2f).
  #pragma unroll
  for (int mt = 0; mt < 2; mt++){
    #pragma unroll
    for (int nt = 0; nt < 4; nt++){
      #pragma unroll
      for (int rg = 0; rg < 4; rg++){
        int m = M0 + mbase + mt*16 + quad*4 + rg;
        int n = N0 + nbase + nt*16 + l15;
        float vv = acc[mt][nt][rg];
        int bi = m >> 10, si = m & 1023;
        if (n < 768){
          float sv = vv * 0.18033688011112042f;   // 0.125 * log2(e)
          short hv = f2bf(sv);
          int hh = n >> 6, hd = n & 63;
          long o = (((long)(bi*12+hh)*1024) + si)*64 + hd;
          qh[o] = hv; ql[o] = f2bf(sv - bf2f(hv));
        } else if (n < 1536){
          int n2 = n - 768;
          short hv = f2bf(vv);
          int hh = n2 >> 6, hd = n2 & 63;
          long o = (((long)(bi*12+hh)*1024) + si)*64 + hd;
          kh[o] = hv; kl[o] = f2bf(vv - bf2f(hv));
        } else {
          int n2 = n - 1536;
          short hv = f2bf(vv);
          int hh = n2 >> 6, hd = n2 & 63;
          long o = (((long)(bi*12+hh)*64) + hd)*1024 + si;
          vh[o] = hv; vl[o] = f2bf(vv - bf2f(hv));
        }
      }
    }
  }
}

// ---------------- flash attention, split-bf16, causal, split-K=2 ------------
// Work remap: wid = (x + 3*y) & 31 balances per-CU load. Softmax in log2
// domain (exp2f; scale folded in Q).
__global__ __launch_bounds__(256,3) void k_attn(
    const short* __restrict__ qh, const short* __restrict__ ql,
    const short* __restrict__ kh, const short* __restrict__ kl,
    const short* __restrict__ vth, const short* __restrict__ vtl,
    float* __restrict__ po, float* __restrict__ pm, float* __restrict__ pl){
  int wid = (blockIdx.x + 3*blockIdx.y) & 31;
  int qt = wid >> 1, half = wid & 1, bh = blockIdx.y;
  int q0 = qt * 64;
  long base = (long)bh * 1024 * 64;
  int ktb = half ? ((qt + 2) >> 1) : 0;
  int kte = half ? (qt + 1) : ((qt + 2) >> 1);
  __shared__ __align__(16) short skh[64*64], skl[64*64], svh[64*64], svl[64*64];
  __shared__ __align__(16) short sph[4][16*72], spl[4][16*72];
  int tid = threadIdx.x, w = tid >> 6, lane = tid & 63, l15 = lane & 15, quad = lane >> 4;
  bf16x8 qfh[2], qfl[2];
  #pragma unroll
  for (int c = 0; c < 2; c++){
    long qa = base + (long)(q0 + w*16 + l15)*64 + c*32 + quad*8;
    qfh[c] = *(const bf16x8*)(qh + qa);
    qfl[c] = *(const bf16x8*)(ql + qa);
  }
  f32x4 oacc[4];
  #pragma unroll
  for (int i = 0; i < 4; i++) oacc[i] = (f32x4){0.f,0.f,0.f,0.f};
  float m_i[4] = {-1e30f,-1e30f,-1e30f,-1e30f};
  float l_i[4] = {0.f,0.f,0.f,0.f};
  const short* gsrc = (w==0) ? kh : (w==1) ? kl : (w==2) ? vth : vtl;
  short* myb = (w==0) ? skh : (w==1) ? skl : (w==2) ? svh : svl;
  bool isv = (w >= 2);
  int rloc = lane >> 3, pch = lane & 7;
  for (int kt = ktb; kt < kte; kt++){
    #pragma unroll
    for (int j = 0; j < 8; j++){
      int r = j*8 + rloc;
      int c = pch ^ (r & 7);
      long ga = isv ? (base + (long)r*1024 + kt*64 + c*8)
                    : (base + (long)(kt*64 + r)*64 + c*8);
      gl_lds16(gsrc + ga, myb + j*512);
    }
    __syncthreads();
    f32x4 sfr[4];
    #pragma unroll
    for (int nt = 0; nt < 4; nt++){
      f32x4 c = (f32x4){0.f,0.f,0.f,0.f};
      int krow = (nt*16 + l15) * 64;
      #pragma unroll
      for (int ch = 0; ch < 2; ch++){
        int pc = ((ch*4 + quad) ^ (l15 & 7)) * 8;
        bf16x8 kfh = *(const bf16x8*)&skh[krow + pc];
        bf16x8 kfl = *(const bf16x8*)&skl[krow + pc];
        c = MFMA16(qfh[ch], kfh, c);
        c = MFMA16(qfh[ch], kfl, c);
        c = MFMA16(qfl[ch], kfh, c);
      }
      sfr[nt] = c;
    }
    if (kt == qt){
      #pragma unroll
      for (int nt = 0; nt < 4; nt++)
        #pragma unroll
        for (int rg = 0; rg < 4; rg++){
          int kp = nt*16 + l15, qp = w*16 + quad*4 + rg;
          if (kp > qp) sfr[nt][rg] = -1e30f;
        }
    }
    float rmax[4];
    #pragma unroll
    for (int rg = 0; rg < 4; rg++)
      rmax[rg] = fmaxf(fmaxf(sfr[0][rg], sfr[1][rg]), fmaxf(sfr[2][rg], sfr[3][rg]));
    #pragma unroll
    for (int xm = 1; xm < 16; xm <<= 1)
      #pragma unroll
      for (int rg = 0; rg < 4; rg++)
        rmax[rg] = fmaxf(rmax[rg], __shfl_xor(rmax[rg], xm, 64));
    float alpha[4];
    #pragma unroll
    for (int rg = 0; rg < 4; rg++){
      float mn = fmaxf(m_i[rg], rmax[rg]);
      alpha[rg] = exp2f(m_i[rg] - mn);
      m_i[rg] = mn;
    }
    float rsum[4] = {0.f,0.f,0.f,0.f};
    #pragma unroll
    for (int nt = 0; nt < 4; nt++)
      #pragma unroll
      for (int rg = 0; rg < 4; rg++){
        float p = exp2f(sfr[nt][rg] - m_i[rg]);
        sfr[nt][rg] = p; rsum[rg] += p;
      }
    #pragma unroll
    for (int xm = 1; xm < 16; xm <<= 1)
      #pragma unroll
      for (int rg = 0; rg < 4; rg++)
        rsum[rg] += __shfl_xor(rsum[rg], xm, 64);
    #pragma unroll
    for (int rg = 0; rg < 4; rg++) l_i[rg] = l_i[rg]*alpha[rg] + rsum[rg];
    #pragma unroll
    for (int hd = 0; hd < 4; hd++)
      #pragma unroll
      for (int rg = 0; rg < 4; rg++) oacc[hd][rg] *= alpha[rg];
    #pragma unroll
    for (int nt = 0; nt < 4; nt++)
      #pragma unroll
      for (int rg = 0; rg < 4; rg++){
        float p = sfr[nt][rg];
        short hv = f2bf(p);
        sph[w][(quad*4+rg)*72 + nt*16 + l15] = hv;
        spl[w][(quad*4+rg)*72 + nt*16 + l15] = f2bf(p - bf2f(hv));
      }
    bf16x8 pfh[2], pfl[2];
    #pragma unroll
    for (int ch = 0; ch < 2; ch++){
      pfh[ch] = *(const bf16x8*)&sph[w][l15*72 + ch*32 + quad*8];
      pfl[ch] = *(const bf16x8*)&spl[w][l15*72 + ch*32 + quad*8];
    }
    #pragma unroll
    for (int hd = 0; hd < 4; hd++){
      int vrow = (hd*16 + l15) * 64;
      #pragma unroll
      for (int ch = 0; ch < 2; ch++){
        int pc = ((ch*4 + quad) ^ (l15 & 7)) * 8;
        bf16x8 vfh = *(const bf16x8*)&svh[vrow + pc];
        bf16x8 vfl = *(const bf16x8*)&svl[vrow + pc];
        oacc[hd] = MFMA16(pfh[ch], vfh, oacc[hd]);
        oacc[hd] = MFMA16(pfh[ch], vfl, oacc[hd]);
        oacc[hd] = MFMA16(pfl[ch], vfh, oacc[hd]);
      }
    }
    __syncthreads();
  }
  long pb = ((long)(half*24 + bh)*1024);
  #pragma unroll
  for (int hdt = 0; hdt < 4; hdt++)
    #pragma unroll
    for (int rg = 0; rg < 4; rg++){
      int qp = q0 + w*16 + quad*4 + rg;
      po[(pb + qp)*64 + hdt*16 + l15] = oacc[hdt][rg];
    }
  if (l15 == 0){
    #pragma unroll
    for (int rg = 0; rg < 4; rg++){
      int qp = q0 + w*16 + quad*4 + rg;
      pm[pb + qp] = m_i[rg];
      pl[pb + qp] = l_i[rg];
    }
  }
}

// ---------------- attention combine: merge 2 partials -> bf16 hi/lo ---------
// log2-domain partials: weights via exp2f.
__global__ void k_attn_combine(const float* __restrict__ po, const float* __restrict__ pm,
                               const float* __restrict__ pl,
                               short* __restrict__ oh, short* __restrict__ ol){
  int bh = blockIdx.y, tid = threadIdx.x;
  int r = blockIdx.x*64 + (tid >> 2);
  int c0 = (tid & 3) * 16;
  long i0 = (long)bh*1024 + r;
  long i1 = (long)(24 + bh)*1024 + r;
  float m0 = pm[i0], m1 = pm[i1], l0 = pl[i0], l1 = pl[i1];
  float m = fmaxf(m0, m1);
  float a0 = exp2f(m0 - m), a1 = exp2f(m1 - m);
  float inv = 1.f / (a0*l0 + a1*l1);
  a0 *= inv; a1 *= inv;
  int b = bh / 12, hh = bh % 12;
  long ob = ((long)(b*1024 + r))*768 + hh*64 + c0;
  short hv[16], lv[16];
  #pragma unroll
  for (int j = 0; j < 4; j++){
    float4 o0 = *(const float4*)&po[i0*64 + c0 + j*4];
    float4 o1 = *(const float4*)&po[i1*64 + c0 + j*4];
    float vs[4] = {a0*o0.x + a1*o1.x, a0*o0.y + a1*o1.y,
                   a0*o0.z + a1*o1.z, a0*o0.w + a1*o1.w};
    #pragma unroll
    for (int q = 0; q < 4; q++){
      short h = f2bf(vs[q]);
      hv[j*4+q] = h; lv[j*4+q] = f2bf(vs[q] - bf2f(h));
    }
  }
  *(bf16x8*)(oh + ob)     = *(bf16x8*)&hv[0];
  *(bf16x8*)(oh + ob + 8) = *(bf16x8*)&hv[8];
  *(bf16x8*)(ol + ob)     = *(bf16x8*)&lv[0];
  *(bf16x8*)(ol + ob + 8) = *(bf16x8*)&lv[8];
}

// ---------------- split GEMM Wo -> partials, BM=64 BN=128, split-K=2 --------
// grid (32,6,2) = 384 blocks = 1.5/CU. Partials fp32; combine fused into
// k_ln2router.
__global__ __launch_bounds__(256,3) void k_wo(
    const short* __restrict__ Ah, const short* __restrict__ Al,
    const short* __restrict__ Bh, const short* __restrict__ Bl,
    float* __restrict__ p0, float* __restrict__ p1){
  int M0 = blockIdx.x * 64, N0 = blockIdx.y * 128;
  int ks = blockIdx.z;
  int kbeg = ks * 384;
  float* wp = ks ? p1 : p0;
  __shared__ __align__(16) short lah[64*64], lal[64*64], lbh[128*64], lbl[128*64];
  int tid = threadIdx.x;
  int w = tid >> 6, lane = tid & 63, l15 = lane & 15, quad = lane >> 4;
  int mbase = (w & 1) * 32, nbase = (w >> 1) * 64;
  f32x4 acc[2][4];
  #pragma unroll
  for (int i = 0; i < 2; i++)
    #pragma unroll
    for (int j = 0; j < 4; j++) acc[i][j] = (f32x4){0.f,0.f,0.f,0.f};
  int rl = lane >> 3, pch = lane & 7;
  long gA[2], gB[4];
  #pragma unroll
  for (int j = 0; j < 2; j++){
    int r = w*16 + j*8 + rl;
    int c = pch ^ (r & 7);
    gA[j] = (long)(M0 + r)*768 + kbeg + c*8;
  }
  #pragma unroll
  for (int j = 0; j < 4; j++){
    int r = w*32 + j*8 + rl;
    int c = pch ^ (r & 7);
    gB[j] = (long)(N0 + r)*768 + kbeg + c*8;
  }
  for (int k0 = 0; k0 < 384; k0 += 64){
    #pragma unroll
    for (int j = 0; j < 2; j++){
      gl_lds16(Ah + gA[j] + k0, lah + w*1024 + j*512);
      gl_lds16(Al + gA[j] + k0, lal + w*1024 + j*512);
    }
    #pragma unroll
    for (int j = 0; j < 4; j++){
      gl_lds16(Bh + gB[j] + k0, lbh + w*2048 + j*512);
      gl_lds16(Bl + gB[j] + k0, lbl + w*2048 + j*512);
    }
    __syncthreads();
    #pragma unroll
    for (int kk = 0; kk < 2; kk++){
      int swq = ((kk*4 + quad) ^ (l15 & 7)) * 8;
      bf16x8 afh[2], afl[2];
      #pragma unroll
      for (int mt = 0; mt < 2; mt++){
        afh[mt] = *(const bf16x8*)&lah[(mbase+mt*16+l15)*64 + swq];
        afl[mt] = *(const bf16x8*)&lal[(mbase+mt*16+l15)*64 + swq];
      }
      #pragma unroll
      for (int nt = 0; nt < 4; nt++){
        bf16x8 bfh = *(const bf16x8*)&lbh[(nbase+nt*16+l15)*64 + swq];
        bf16x8 bfl = *(const bf16x8*)&lbl[(nbase+nt*16+l15)*64 + swq];
        #pragma unroll
        for (int mt = 0; mt < 2; mt++){
          acc[mt][nt] = MFMA16(afh[mt], bfh, acc[mt][nt]);
          acc[mt][nt] = MFMA16(afh[mt], bfl, acc[mt][nt]);
          acc[mt][nt] = MFMA16(afl[mt], bfh, acc[mt][nt]);
        }
      }
    }
    __syncthreads();
  }
  #pragma unroll
  for (int mt = 0; mt < 2; mt++)
    #pragma unroll
    for (int nt = 0; nt < 4; nt++)
      #pragma unroll
      for (int rg = 0; rg < 4; rg++){
        int m = M0 + mbase + mt*16 + quad*4 + rg;
        int n = N0 + nbase + nt*16 + l15;
        wp[(long)m*768 + n] = acc[mt][nt][rg];
      }
}

// ---------------- fused: h = P0+P1+x+bo; LN2; router (no global atomics) ----
// grid 256 x 256thr; wave wv handles tokens wv*2, wv*2+1. Vectorized float4.
__global__ void k_ln2router(const float* __restrict__ p0, const float* __restrict__ p1,
                            const float* __restrict__ x, const float* __restrict__ bo,
                            const float* __restrict__ g, const float* __restrict__ bb,
                            const float* __restrict__ Wr, const float* __restrict__ br,
                            float* __restrict__ hout, short* __restrict__ xn2,
                            int* __restrict__ sel, float* __restrict__ gw){
  int wv = (blockIdx.x*256 + threadIdx.x) >> 6;
  int lane = threadIdx.x & 63;
  #pragma unroll
  for (int rep = 0; rep < 2; rep++){
    int t = wv*2 + rep;
    float4 hv[3];
    #pragma unroll
    for (int j = 0; j < 3; j++){
      long i = (long)t*192 + j*64 + lane;
      float4 a  = ((const float4*)p0)[i];
      float4 b  = ((const float4*)p1)[i];
      float4 xx = ((const float4*)x)[i];
      float4 bv = ((const float4*)bo)[j*64 + lane];
      float4 h;
      h.x = a.x + b.x + xx.x + bv.x;
      h.y = a.y + b.y + xx.y + bv.y;
      h.z = a.z + b.z + xx.z + bv.z;
      h.w = a.w + b.w + xx.w + bv.w;
      ((float4*)hout)[i] = h;
      hv[j] = h;
    }
    float s = 0.f, q = 0.f;
    #pragma unroll
    for (int j = 0; j < 3; j++){
      s += hv[j].x + hv[j].y + hv[j].z + hv[j].w;
      q += hv[j].x*hv[j].x + hv[j].y*hv[j].y + hv[j].z*hv[j].z + hv[j].w*hv[j].w;
    }
    #pragma unroll
    for (int xm = 1; xm < 64; xm <<= 1){ s += __shfl_xor(s, xm, 64); q += __shfl_xor(q, xm, 64); }
    float mean = s * (1.f/768.f);
    float var  = q * (1.f/768.f) - mean*mean;
    float inv  = 1.f / sqrtf(var + 1e-5f);
    float part[8] = {0,0,0,0,0,0,0,0};
    #pragma unroll
    for (int j = 0; j < 3; j++){
      int d0 = (j*64 + lane) * 4;
      float4 gv = ((const float4*)g)[j*64 + lane];
      float4 bbv = ((const float4*)bb)[j*64 + lane];
      float xn0 = (hv[j].x - mean)*inv*gv.x + bbv.x;
      float xn1 = (hv[j].y - mean)*inv*gv.y + bbv.y;
      float xn2v = (hv[j].z - mean)*inv*gv.z + bbv.z;
      float xn3 = (hv[j].w - mean)*inv*gv.w + bbv.w;
      bf16x4 pk = (bf16x4){f2bf(xn0), f2bf(xn1), f2bf(xn2v), f2bf(xn3)};
      *(bf16x4*)&xn2[(long)t*768 + d0] = pk;
      #pragma unroll
      for (int e = 0; e < 8; e++){
        part[e] += xn0 * Wr[(d0+0)*8 + e];
        part[e] += xn1 * Wr[(d0+1)*8 + e];
        part[e] += xn2v * Wr[(d0+2)*8 + e];
        part[e] += xn3 * Wr[(d0+3)*8 + e];
      }
    }
    #pragma unroll
    for (int xm = 1; xm < 64; xm <<= 1)
      #pragma unroll
      for (int e = 0; e < 8; e++) part[e] += __shfl_xor(part[e], xm, 64);
    if (lane == 0){
      float lg[8];
      #pragma unroll
      for (int e = 0; e < 8; e++) lg[e] = part[e] + br[e];
      int i1 = 0;
      for (int e = 1; e < 8; e++) if (lg[e] > lg[i1]) i1 = e;
      int i2 = -1;
      for (int e = 0; e < 8; e++){ if (e == i1) continue; if (i2 < 0 || lg[e] > lg[i2]) i2 = e; }
      float e2 = expf(lg[i2] - lg[i1]);
      float is = 1.f / (1.f + e2);
      gw[t*2]   = is;
      gw[t*2+1] = e2 * is;
      sel[t*2]   = i1;
      sel[t*2+1] = i2;
    }
  }
}

// single-block compaction: wave-aggregated ballot histogram + placement.
__global__ void k_build(const int* __restrict__ sel, int* __restrict__ poffs,
                        int* __restrict__ mbc, int* __restrict__ ptot,
                        int* __restrict__ pperm, int* __restrict__ inv){
  __shared__ int cnt8[8], cur[8], wbase[16][8];
  int tid = threadIdx.x;   // 1024
  int lane = tid & 63, wv = tid >> 6;
  if (tid < 8) cnt8[tid] = 0;
  __syncthreads();
  int sv[4];
  #pragma unroll
  for (int r = 0; r < 4; r++){
    sv[r] = sel[tid + r*1024];
    #pragma unroll
    for (int e = 0; e < 8; e++){
      unsigned long long mk = __ballot(sv[r] == e);
      if (lane == 0) atomicAdd(&cnt8[e], (int)__popcll(mk));
    }
  }
  __syncthreads();
  if (tid == 0){
    int p = 0;
    for (int e = 0; e < 8; e++){
      cur[e] = p; poffs[e] = p;
      int pc = (cnt8[e] + 127) & ~127;
      mbc[e] = pc >> 7;
      p += pc;
    }
    *ptot = p;
  }
  __syncthreads();
  #pragma unroll
  for (int r = 0; r < 5; r++) pperm[tid + r*1024] = -1;
  __syncthreads();
  unsigned long long lmask = (1ull << lane) - 1ull;
  #pragma unroll
  for (int r = 0; r < 4; r++){
    int s = sv[r];
    unsigned long long mk[8];
    #pragma unroll
    for (int e = 0; e < 8; e++) mk[e] = __ballot(s == e);
    if (lane == 0){
      #pragma unroll
      for (int e = 0; e < 8; e++)
        wbase[wv][e] = atomicAdd(&cur[e], (int)__popcll(mk[e]));
    }
    unsigned long long mks = 0;
    #pragma unroll
    for (int e = 0; e < 8; e++) if (s == e) mks = mk[e];   // static indexing (rule #20)
    int pos = wbase[wv][s] + (int)__popcll(mks & lmask);
    int i = tid + r*1024;
    pperm[pos] = i;
    inv[i] = pos;
  }
}

// ---------------- MoE GEMM1: h1[p] = gelu(xn2[tok(p)] @ W1T[e] + b1) --------
// grid (192 = e*24+n weight-tile, 16 = Mblk). Round-1 proven config
// (CONTROL for the moe2 pipeline experiment this round).
__global__ __launch_bounds__(256,3) void k_moe1(
    const short* __restrict__ xn2, const short* __restrict__ W1T,
    const float* __restrict__ b1,
    const int* __restrict__ poffs, const int* __restrict__ mbc,
    const int* __restrict__ pperm, short* __restrict__ h1){
  int t = blockIdx.x;
  int e = t / 24, n = t % 24;
  if ((int)blockIdx.y >= mbc[e]) return;
  int M0 = poffs[e] + blockIdx.y * 128;
  int N0 = n * 128;
  const short* Bp = W1T + (long)e * 3072 * 768;
  __shared__ __align__(16) short la[128*64], lb[128*64];
  __shared__ int rtok[128];
  int tid = threadIdx.x, w = tid >> 6, lane = tid & 63, l15 = lane & 15, quad = lane >> 4;
  if (tid < 128) rtok[tid] = pperm[M0 + tid];
  __syncthreads();
  int rl = lane >> 3, pch = lane & 7;
  long gA[4], gB[4];
  #pragma unroll
  for (int j = 0; j < 4; j++){
    int r = w*32 + j*8 + rl;
    int c = pch ^ (r & 7);
    int tk = rtok[r]; tk = (tk >= 0) ? (tk >> 1) : 0;
    gA[j] = (long)tk*768 + c*8;
    gB[j] = (long)(N0 + r)*768 + c*8;
  }
  short* ldA = la + w*2048;
  short* ldB = lb + w*2048;
  f32x4 acc[4][4];
  #pragma unroll
  for (int i = 0; i < 4; i++)
    #pragma unroll
    for (int j = 0; j < 4; j++) acc[i][j] = (f32x4){0.f,0.f,0.f,0.f};
  int mbase = (w & 1) * 64, nbase = (w >> 1) * 64;
  for (int k0 = 0; k0 < 768; k0 += 64){
    #pragma unroll
    for (int j = 0; j < 4; j++) gl_lds16(xn2 + gA[j] + k0, ldA + j*512);
    #pragma unroll
    for (int j = 0; j < 4; j++) gl_lds16(Bp  + gB[j] + k0, ldB + j*512);
    __syncthreads();
    #pragma unroll
    for (int kk = 0; kk < 2; kk++){
      int swq = ((kk*4 + quad) ^ (l15 & 7)) * 8;
      bf16x8 af[4];
      #pragma unroll
      for (int mt = 0; mt < 4; mt++)
        af[mt] = *(const bf16x8*)&la[(mbase+mt*16+l15)*64 + swq];
      #pragma unroll
      for (int nt = 0; nt < 4; nt++){
        bf16x8 bf = *(const bf16x8*)&lb[(nbase+nt*16+l15)*64 + swq];
        #pragma unroll
        for (int mt = 0; mt < 4; mt++) acc[mt][nt] = MFMA16(af[mt], bf, acc[mt][nt]);
      }
    }
    __syncthreads();
  }
  #pragma unroll
  for (int mt = 0; mt < 4; mt++)
    #pragma unroll
    for (int nt = 0; nt < 4; nt++)
      #pragma unroll
      for (int rg = 0; rg < 4; rg++){
        int ml = mbase + mt*16 + quad*4 + rg;
        if (rtok[ml] >= 0){
          int nn = N0 + nbase + nt*16 + l15;
          float vv = acc[mt][nt][rg] + b1[e*3072 + nn];
          float gl = 0.5f * vv * (1.f + erff(vv * 0.70710678118654752f));
          h1[(long)(M0 + ml)*3072 + nn] = f2bf(gl);
        }
      }
}

// ---------------- MoE GEMM2: E[ks][slot] = h1 @ W2T[e](+b2), split-K=4 ------
// EXPERIMENT (T3+T4): double-buffered prefetch with COUNTED vmcnt + raw
// s_barrier — wait vmcnt(8) drains only the PREVIOUS step's loads; the 8
// prefetched loads stay in flight across the barrier (never drain to 0 in
// the loop). sched_barrier(0) fences pin ds_reads between barriers
// (rule #18/m152). LDS 64KB -> 2 blocks/CU.
__global__ __launch_bounds__(256,2) void k_moe2(
    const short* __restrict__ h1, const short* __restrict__ W2T,
    const float* __restrict__ b2,
    const int* __restrict__ poffs, const int* __restrict__ mbc,
    float* __restrict__ e0, float* __restrict__ e1,
    float* __restrict__ e2, float* __restrict__ e3){
  int t = blockIdx.x;
  int e = t / 24, r24 = t % 24;
  int n = r24 >> 2, ks = r24 & 3;
  if ((int)blockIdx.y >= mbc[e]) return;
  int M0 = poffs[e] + blockIdx.y * 128;
  int N0 = n * 128;
  int kbeg = ks * 768;
  const short* Bp = W2T + (long)e * 768 * 3072;
  float* eo = (ks == 0) ? e0 : (ks == 1) ? e1 : (ks == 2) ? e2 : e3;
  __shared__ __align__(16) short la[2][128*64], lb[2][128*64];
  int tid = threadIdx.x, w = tid >> 6, lane = tid & 63, l15 = lane & 15, quad = lane >> 4;
  int rl = lane >> 3, pch = lane & 7;
  long gA[4], gB[4];
  #pragma unroll
  for (int j = 0; j < 4; j++){
    int r = w*32 + j*8 + rl;
    int c = pch ^ (r & 7);
    gA[j] = (long)(M0 + r)*3072 + kbeg + c*8;
    gB[j] = (long)(N0 + r)*3072 + kbeg + c*8;
  }
  f32x4 acc[4][4];
  #pragma unroll
  for (int i = 0; i < 4; i++)
    #pragma unroll
    for (int j = 0; j < 4; j++) acc[i][j] = (f32x4){0.f,0.f,0.f,0.f};
  int mbase = (w & 1) * 64, nbase = (w >> 1) * 64;
  // prologue: stage buf0 (8 loads in flight)
  #pragma unroll
  for (int j = 0; j < 4; j++){
    gl_lds16(h1 + gA[j], &la[0][w*2048 + j*512]);
    gl_lds16(Bp + gB[j], &lb[0][w*2048 + j*512]);
  }
  for (int st = 0; st < 12; st++){
    int cur = st & 1;
    if (st + 1 < 12){
      // issue next step's 8 loads into the other buffer (16 now in flight)
      #pragma unroll
      for (int j = 0; j < 4; j++){
        gl_lds16(h1 + gA[j] + (st+1)*64, &la[cur^1][w*2048 + j*512]);
        gl_lds16(Bp + gB[j] + (st+1)*64, &lb[cur^1][w*2048 + j*512]);
      }
      asm volatile("s_waitcnt vmcnt(8)" ::: "memory");   // buf[cur] ready; 8 stay in flight
    } else {
      asm volatile("s_waitcnt vmcnt(0)" ::: "memory");   // last step: drain all
    }
    __builtin_amdgcn_sched_barrier(0);
    __builtin_amdgcn_s_barrier();                         // cross-wave: buf[cur] complete
    __builtin_amdgcn_sched_barrier(0);
    #pragma unroll
    for (int kk = 0; kk < 2; kk++){
      int swq = ((kk*4 + quad) ^ (l15 & 7)) * 8;
      bf16x8 af[4];
      #pragma unroll
      for (int mt = 0; mt < 4; mt++)
        af[mt] = *(const bf16x8*)&la[cur][(mbase+mt*16+l15)*64 + swq];
      #pragma unroll
      for (int nt = 0; nt < 4; nt++){
        bf16x8 bf = *(const bf16x8*)&lb[cur][(nbase+nt*16+l15)*64 + swq];
        #pragma unroll
        for (int mt = 0; mt < 4; mt++) acc[mt][nt] = MFMA16(af[mt], bf, acc[mt][nt]);
      }
    }
    __builtin_amdgcn_sched_barrier(0);
    __builtin_amdgcn_s_barrier();                         // all reads of buf[cur] done
    __builtin_amdgcn_sched_barrier(0);                    // before st+1 overwrites it
  }
  #pragma unroll
  for (int mt = 0; mt < 4; mt++)
    #pragma unroll
    for (int nt = 0; nt < 4; nt++)
      #pragma unroll
      for (int rg = 0; rg < 4; rg++){
        int ml = mbase + mt*16 + quad*4 + rg;
        int nn = N0 + nbase + nt*16 + l15;
        float vv = acc[mt][nt][rg] + ((ks == 0) ? b2[e*768 + nn] : 0.f);
        eo[(long)(M0 + ml)*768 + nn] = vv;
      }
}

// ---------------- final combine: out = h + Σ_slot g*(E0+E1+E2+E3)[slot] -----
__global__ void k_combine(const float* __restrict__ h,
                          const float* __restrict__ e0, const float* __restrict__ e1,
                          const float* __restrict__ e2, const float* __restrict__ e3,
                          const int* __restrict__ inv, const float* __restrict__ gw,
                          float* __restrict__ out){
  int i = blockIdx.x * 256 + threadIdx.x;     // 393216 float4s
  int t = i / 192, c = i - t * 192;
  int s0 = inv[2*t], s1 = inv[2*t+1];
  float g0 = gw[2*t], g1 = gw[2*t+1];
  float4 a  = ((const float4*)h)[i];
  long o0 = (long)s0*192 + c, o1 = (long)s1*192 + c;
  float4 x0 = ((const float4*)e0)[o0];
  float4 y0 = ((const float4*)e1)[o0];
  float4 z0 = ((const float4*)e2)[o0];
  float4 w0 = ((const float4*)e3)[o0];
  float4 x1 = ((const float4*)e0)[o1];
  float4 y1 = ((const float4*)e1)[o1];
  float4 z1 = ((const float4*)e2)[o1];
  float4 w1 = ((const float4*)e3)[o1];
  float4 o;
  o.x = a.x + g0*(x0.x + y0.x + z0.x + w0.x) + g1*(x1.x + y1.x + z1.x + w1.x);
  o.y = a.y + g0*(x0.y + y0.y + z0.y + w0.y) + g1*(x1.y + y1.y + z1.y + w1.y);
  o.z = a.z + g0*(x0.z + y0.z + z0.z + w0.z) + g1*(x1.z + y1.z + z1.z + w1.z);
  o.w = a.w + g0*(x0.w + y0.w + z0.w + w0.w) + g1*(x1.w + y1.w + z1.w + w1.w);
  ((float4*)out)[i] = o;
}

// ---------------- launcher ----------------
extern "C" void kernel_launch(void* const* d_in, const int* in_sizes, int n_in,
                              void* d_out, int out_size, void* d_ws, size_t ws_size,
                              hipStream_t stream){
  const float* x    = (const float*)d_in[0];
  const float* ln1g = (const float*)d_in[1];
  const float* ln1b = (const float*)d_in[2];
  const float* Wq   = (const float*)d_in[3];
  const float* Wk   = (const float*)d_in[4];
  const float* Wv   = (const float*)d_in[5];
  const float* Wo   = (const float*)d_in[6];
  const float* bo   = (const float*)d_in[7];
  const float* ln2g = (const float*)d_in[8];
  const float* ln2b = (const float*)d_in[9];
  const float* Wr   = (const float*)d_in[10];
  const float* br   = (const float*)d_in[11];
  const float* W1   = (const float*)d_in[12];
  const float* b1   = (const float*)d_in[13];
  const float* W2   = (const float*)d_in[14];
  const float* b2   = (const float*)d_in[15];

  char* ws = (char*)d_ws;
  size_t off = 0;
  auto alloc = [&](size_t bytes) -> void* {
    void* p = ws + off;
    off += (bytes + 255) & ~(size_t)255;
    return p;
  };
  short* WQKVH = (short*)alloc(2304l*768*2);
  short* WQKVL = (short*)alloc(2304l*768*2);
  short* WOH   = (short*)alloc(768l*768*2);
  short* WOL   = (short*)alloc(768l*768*2);
  short* W1T   = (short*)alloc(8l*3072*768*2);
  short* W2T   = (short*)alloc(8l*768*3072*2);
  short* XN1H  = (short*)alloc(2048l*768*2);
  short* XN1L  = (short*)alloc(2048l*768*2);
  short* QH    = (short*)alloc(2048l*768*2);
  short* QL    = (short*)alloc(2048l*768*2);
  short* KH    = (short*)alloc(2048l*768*2);
  short* KL    = (short*)alloc(2048l*768*2);
  short* VTH   = (short*)alloc(2048l*768*2);
  short* VTL   = (short*)alloc(2048l*768*2);
  short* ATH   = (short*)alloc(2048l*768*2);
  short* ATL   = (short*)alloc(2048l*768*2);
  float* HBUF  = (float*)alloc(2048l*768*4);
  short* XN2   = (short*)alloc(2048l*768*2);
  short* H1    = (short*)alloc(5120l*3072*2);
  float* E0    = (float*)alloc(5120l*768*4);
  float* E1    = (float*)alloc(5120l*768*4);
  float* PO    = (float*)alloc(2l*24*1024*64*4);
  float* PM    = (float*)alloc(2l*24*1024*4);
  float* PL    = (float*)alloc(2l*24*1024*4);
  int*   POFF  = (int*)alloc(8*4);
  int*   MBC   = (int*)alloc(8*4);
  int*   PTOT  = (int*)alloc(4);
  int*   SEL   = (int*)alloc(4096*4);
  int*   PPERM = (int*)alloc(5120*4);
  int*   INV   = (int*)alloc(4096*4);
  float* GW    = (float*)alloc(4096*4);
  (void)ws_size; (void)in_sizes; (void)n_in; (void)out_size;

  // E2/E3: alias the attention-path buffers (XN1H..ATL = 10 x 3,145,728 B
  // = exactly 2 x 5120*768*4 B). All consumers of that region (k_qkv,
  // k_attn, k_wo) complete before k_moe2 runs on the same stream.
  float* E2 = (float*)XN1H;
  float* E3 = E2 + 5120l*768;
  // WP0/WP1: alias PO (12.58 MB = exactly 2 x 2048*768*4). k_attn_combine
  // (PO's last consumer) completes before k_wo writes on the same stream.
  float* WP0 = PO;
  float* WP1 = PO + 2048l*768;

  // weight prep: 4 square transposes in ONE launch; W1/W2 separate
  k_transpose4<<<dim3(12,12,4),256,0,stream>>>(
      Wq, Wk, Wv, Wo,
      WQKVH,             WQKVL,
      WQKVH + 768l*768,  WQKVL + 768l*768,
      WQKVH + 1536l*768, WQKVL + 1536l*768,
      WOH, WOL);
  k_transpose<<<dim3(48,12,8),256,0,stream>>>(W1, 768l*3072, W1T, nullptr, 3072l*768, 768, 3072);
  k_transpose<<<dim3(12,48,8),256,0,stream>>>(W2, 3072l*768, W2T, nullptr, 768l*3072, 3072, 768);

  // attention path (split-bf16 precision)
  k_ln1<<<2048,256,0,stream>>>(x, ln1g, ln1b, XN1H, XN1L);
  k_qkv<<<dim3(32,18),256,0,stream>>>(XN1H, XN1L, WQKVH, WQKVL, QH, QL, KH, KL, VTH, VTL);
  k_attn<<<dim3(32,24),256,0,stream>>>(QH, QL, KH, KL, VTH, VTL, PO, PM, PL);
  k_attn_combine<<<dim3(16,24),256,0,stream>>>(PO, PM, PL, ATH, ATL);
  k_wo<<<dim3(32,6,2),256,0,stream>>>(ATH, ATL, WOH, WOL, WP0, WP1);

  // fused residual+LN2+router, then MoE (no global atomics)
  k_ln2router<<<256,256,0,stream>>>(WP0, WP1, x, bo, ln2g, ln2b, Wr, br,
                                    HBUF, XN2, SEL, GW);
  k_build<<<1,1024,0,stream>>>(SEL, POFF, MBC, PTOT, PPERM, INV);
  k_moe1<<<dim3(192,16),256,0,stream>>>(XN2, W1T, b1, POFF, MBC, PPERM, H1);
  k_moe2<<<dim3(192,16),256,0,stream>>>(H1, W2T, b2, POFF, MBC, E0, E1, E2, E3);
  k_combine<<<1536,256,0,stream>>>(HBUF, E0, E1, E2, E3, INV, GW, (float*)d_out);
}

// Round 9
// 435.389 us; speedup vs baseline: 1.1783x; 1.1783x over previous
//
#include <hip/hip_runtime.h>

// ---------------- common helpers ----------------
using bf16x8 = __attribute__((ext_vector_type(8))) short;
using bf16x4 = __attribute__((ext_vector_type(4))) short;
using f32x4  = __attribute__((ext_vector_type(4))) float;

#define DEV __device__ __forceinline__

DEV short f2bf(float x){
  unsigned u = __float_as_uint(x);
  u += 0x7fffu + ((u >> 16) & 1u);
  return (short)(u >> 16);
}
DEV float bf2f(short h){ return __uint_as_float(((unsigned)(unsigned short)h) << 16); }

#define MFMA16(a,b,c) __builtin_amdgcn_mfma_f32_16x16x32_bf16(a,b,c,0,0,0)

// async global->LDS, 16B per lane; LDS dest is wave-uniform base + lane*16
DEV void gl_lds16(const void* g, void* l){
  __builtin_amdgcn_global_load_lds(
      (const __attribute__((address_space(1))) unsigned*)g,
      (__attribute__((address_space(3))) unsigned*)l, 16, 0, 0);
}

// Problem constants: B=2 S=1024 D=768 H=12 HD=64 E=8 DF=3072 K=2, T=2048

// ---------------- transpose + fp32->bf16(hi/lo) convert, 64x64 tiles -------
__global__ void k_transpose(const float* __restrict__ src, long sbatch,
                            short* __restrict__ dhi, short* __restrict__ dlo, long dbatch,
                            int R, int C){
  __shared__ float tile[64][65];
  const float* s = src + (long)blockIdx.z * sbatch;
  int c0 = blockIdx.x * 64, r0 = blockIdx.y * 64;
  int tx = threadIdx.x & 15, ty = threadIdx.x >> 4;   // 16 col-quads x 16 rows
  #pragma unroll
  for (int i = 0; i < 4; i++){
    int r = ty + 16*i;
    float4 v = *(const float4*)&s[(long)(r0 + r) * C + c0 + tx*4];
    tile[r][tx*4+0] = v.x; tile[r][tx*4+1] = v.y;
    tile[r][tx*4+2] = v.z; tile[r][tx*4+3] = v.w;
  }
  __syncthreads();
  int rseg = (threadIdx.x & 7) * 8;                   // 8-row segment
  #pragma unroll
  for (int p = 0; p < 2; p++){
    int col = (threadIdx.x >> 3) + 32*p;              // 32 cols per pass
    short hv[8], lv[8];
    #pragma unroll
    for (int k = 0; k < 8; k++){
      float v = tile[rseg + k][col];
      hv[k] = f2bf(v);
      lv[k] = f2bf(v - bf2f(hv[k]));
    }
    long o = (long)blockIdx.z * dbatch + (long)(c0 + col) * R + r0 + rseg;
    *(bf16x8*)&dhi[o] = *(bf16x8*)&hv[0];
    if (dlo) *(bf16x8*)&dlo[o] = *(bf16x8*)&lv[0];
  }
}

// 4 square 768x768 weight transposes in ONE launch (z selects the matrix).
__global__ void k_transpose4(const float* __restrict__ s0, const float* __restrict__ s1,
                             const float* __restrict__ s2, const float* __restrict__ s3,
                             short* __restrict__ d0h, short* __restrict__ d0l,
                             short* __restrict__ d1h, short* __restrict__ d1l,
                             short* __restrict__ d2h, short* __restrict__ d2l,
                             short* __restrict__ d3h, short* __restrict__ d3l){
  int z = blockIdx.z;
  const float* s = (z==0) ? s0 : (z==1) ? s1 : (z==2) ? s2 : s3;
  short* dh = (z==0) ? d0h : (z==1) ? d1h : (z==2) ? d2h : d3h;
  short* dl = (z==0) ? d0l : (z==1) ? d1l : (z==2) ? d2l : d3l;
  __shared__ float tile[64][65];
  int c0 = blockIdx.x * 64, r0 = blockIdx.y * 64;
  int tx = threadIdx.x & 15, ty = threadIdx.x >> 4;
  #pragma unroll
  for (int i = 0; i < 4; i++){
    int r = ty + 16*i;
    float4 v = *(const float4*)&s[(long)(r0 + r) * 768 + c0 + tx*4];
    tile[r][tx*4+0] = v.x; tile[r][tx*4+1] = v.y;
    tile[r][tx*4+2] = v.z; tile[r][tx*4+3] = v.w;
  }
  __syncthreads();
  int rseg = (threadIdx.x & 7) * 8;
  #pragma unroll
  for (int p = 0; p < 2; p++){
    int col = (threadIdx.x >> 3) + 32*p;
    short hv[8], lv[8];
    #pragma unroll
    for (int k = 0; k < 8; k++){
      float v = tile[rseg + k][col];
      hv[k] = f2bf(v);
      lv[k] = f2bf(v - bf2f(hv[k]));
    }
    long o = (long)(c0 + col) * 768 + r0 + rseg;
    *(bf16x8*)&dh[o] = *(bf16x8*)&hv[0];
    *(bf16x8*)&dl[o] = *(bf16x8*)&lv[0];
  }
}

// ---------------- LayerNorm1: x -> xn1 hi/lo bf16 ----------------
__global__ void k_ln1(const float* __restrict__ x, const float* __restrict__ g,
                      const float* __restrict__ bb,
                      short* __restrict__ xh, short* __restrict__ xl){
  int t = blockIdx.x, tid = threadIdx.x;
  const float* xr = x + (long)t * 768;
  float v[3];
  #pragma unroll
  for (int j = 0; j < 3; j++) v[j] = xr[tid + 256*j];
  float s = v[0]+v[1]+v[2];
  float q = v[0]*v[0]+v[1]*v[1]+v[2]*v[2];
  #pragma unroll
  for (int o = 32; o > 0; o >>= 1){ s += __shfl_down(s,o,64); q += __shfl_down(q,o,64); }
  __shared__ float ss[4], qs[4];
  int w = tid >> 6;
  if ((tid & 63) == 0){ ss[w] = s; qs[w] = q; }
  __syncthreads();
  float St = ss[0]+ss[1]+ss[2]+ss[3], Qt = qs[0]+qs[1]+qs[2]+qs[3];
  float mean = St * (1.f/768.f);
  float var  = Qt * (1.f/768.f) - mean*mean;
  float inv  = 1.f / sqrtf(var + 1e-5f);
  #pragma unroll
  for (int j = 0; j < 3; j++){
    int d = tid + 256*j;
    float xn = (v[j]-mean)*inv*g[d] + bb[d];
    short hv = f2bf(xn);
    xh[(long)t*768 + d] = hv;
    xl[(long)t*768 + d] = f2bf(xn - bf2f(hv));
  }
}

// ---------------- split-bf16 GEMM: qkv = xn1 @ Wqkv -------------------------
// BM=64 BN=128: grid (32,18) = 576 blocks = 2.25/CU. LDS 48KB -> 3 blocks/CU.
__global__ __launch_bounds__(256,3) void k_qkv(
    const short* __restrict__ Ah, const short* __restrict__ Al,
    const short* __restrict__ Bh, const short* __restrict__ Bl,
    short* __restrict__ qh, short* __restrict__ ql,
    short* __restrict__ kh, short* __restrict__ kl,
    short* __restrict__ vh, short* __restrict__ vl){
  int M0 = blockIdx.x * 64, N0 = blockIdx.y * 128;
  __shared__ __align__(16) short lah[64*64], lal[64*64], lbh[128*64], lbl[128*64];
  int tid = threadIdx.x;
  int w = tid >> 6, lane = tid & 63, l15 = lane & 15, quad = lane >> 4;
  int mbase = (w & 1) * 32, nbase = (w >> 1) * 64;
  f32x4 acc[2][4];
  #pragma unroll
  for (int i = 0; i < 2; i++)
    #pragma unroll
    for (int j = 0; j < 4; j++) acc[i][j] = (f32x4){0.f,0.f,0.f,0.f};
  int rl = lane >> 3, pch = lane & 7;
  long gA[2], gB[4];
  #pragma unroll
  for (int j = 0; j < 2; j++){
    int r = w*16 + j*8 + rl;
    int c = pch ^ (r & 7);
    gA[j] = (long)(M0 + r)*768 + c*8;
  }
  #pragma unroll
  for (int j = 0; j < 4; j++){
    int r = w*32 + j*8 + rl;
    int c = pch ^ (r & 7);
    gB[j] = (long)(N0 + r)*768 + c*8;
  }
  for (int k0 = 0; k0 < 768; k0 += 64){
    #pragma unroll
    for (int j = 0; j < 2; j++){
      gl_lds16(Ah + gA[j] + k0, lah + w*1024 + j*512);
      gl_lds16(Al + gA[j] + k0, lal + w*1024 + j*512);
    }
    #pragma unroll
    for (int j = 0; j < 4; j++){
      gl_lds16(Bh + gB[j] + k0, lbh + w*2048 + j*512);
      gl_lds16(Bl + gB[j] + k0, lbl + w*2048 + j*512);
    }
    __syncthreads();
    #pragma unroll
    for (int kk = 0; kk < 2; kk++){
      int swq = ((kk*4 + quad) ^ (l15 & 7)) * 8;
      bf16x8 afh[2], afl[2];
      #pragma unroll
      for (int mt = 0; mt < 2; mt++){
        afh[mt] = *(const bf16x8*)&lah[(mbase+mt*16+l15)*64 + swq];
        afl[mt] = *(const bf16x8*)&lal[(mbase+mt*16+l15)*64 + swq];
      }
      #pragma unroll
      for (int nt = 0; nt < 4; nt++){
        bf16x8 bfh = *(const bf16x8*)&lbh[(nbase+nt*16+l15)*64 + swq];
        bf16x8 bfl = *(const bf16x8*)&lbl[(nbase+nt*16+l15)*64 + swq];
        #pragma unroll
        for (int mt = 0; mt < 2; mt++){
          acc[mt][nt] = MFMA16(afh[mt], bfh, acc[mt][nt]);
          acc[mt][nt] = MFMA16(afh[mt], bfl, acc[mt][nt]);
          acc[mt][nt] = MFMA16(afl[mt], bfh, acc[mt][nt]);
        }
      }
    }
    __syncthreads();
  }
  // epilogue: scatter into q[bh][s][hd], k[bh][s][hd], vT[bh][hd][s]
  // Q folds 1/sqrt(HD) * log2(e): softmax runs in log2 domain (exp2f).
  #pragma unroll
  for (int mt = 0; mt < 2; mt++){
    #pragma unroll
    for (int nt = 0; nt < 4; nt++){
      #pragma unroll
      for (int rg = 0; rg < 4; rg++){
        int m = M0 + mbase + mt*16 + quad*4 + rg;
        int n = N0 + nbase + nt*16 + l15;
        float vv = acc[mt][nt][rg];
        int bi = m >> 10, si = m & 1023;
        if (n < 768){
          float sv = vv * 0.18033688011112042f;   // 0.125 * log2(e)
          short hv = f2bf(sv);
          int hh = n >> 6, hd = n & 63;
          long o = (((long)(bi*12+hh)*1024) + si)*64 + hd;
          qh[o] = hv; ql[o] = f2bf(sv - bf2f(hv));
        } else if (n < 1536){
          int n2 = n - 768;
          short hv = f2bf(vv);
          int hh = n2 >> 6, hd = n2 & 63;
          long o = (((long)(bi*12+hh)*1024) + si)*64 + hd;
          kh[o] = hv; kl[o] = f2bf(vv - bf2f(hv));
        } else {
          int n2 = n - 1536;
          short hv = f2bf(vv);
          int hh = n2 >> 6, hd = n2 & 63;
          long o = (((long)(bi*12+hh)*64) + hd)*1024 + si;
          vh[o] = hv; vl[o] = f2bf(vv - bf2f(hv));
        }
      }
    }
  }
}

// ---------------- flash attention, split-bf16, causal, split-K=2 ------------
// Work remap: wid = (x + 3*y) & 31 balances per-CU load. Softmax in log2
// domain (exp2f; scale folded in Q).
__global__ __launch_bounds__(256,3) void k_attn(
    const short* __restrict__ qh, const short* __restrict__ ql,
    const short* __restrict__ kh, const short* __restrict__ kl,
    const short* __restrict__ vth, const short* __restrict__ vtl,
    float* __restrict__ po, float* __restrict__ pm, float* __restrict__ pl){
  int wid = (blockIdx.x + 3*blockIdx.y) & 31;
  int qt = wid >> 1, half = wid & 1, bh = blockIdx.y;
  int q0 = qt * 64;
  long base = (long)bh * 1024 * 64;
  int ktb = half ? ((qt + 2) >> 1) : 0;
  int kte = half ? (qt + 1) : ((qt + 2) >> 1);
  __shared__ __align__(16) short skh[64*64], skl[64*64], svh[64*64], svl[64*64];
  __shared__ __align__(16) short sph[4][16*72], spl[4][16*72];
  int tid = threadIdx.x, w = tid >> 6, lane = tid & 63, l15 = lane & 15, quad = lane >> 4;
  bf16x8 qfh[2], qfl[2];
  #pragma unroll
  for (int c = 0; c < 2; c++){
    long qa = base + (long)(q0 + w*16 + l15)*64 + c*32 + quad*8;
    qfh[c] = *(const bf16x8*)(qh + qa);
    qfl[c] = *(const bf16x8*)(ql + qa);
  }
  f32x4 oacc[4];
  #pragma unroll
  for (int i = 0; i < 4; i++) oacc[i] = (f32x4){0.f,0.f,0.f,0.f};
  float m_i[4] = {-1e30f,-1e30f,-1e30f,-1e30f};
  float l_i[4] = {0.f,0.f,0.f,0.f};
  const short* gsrc = (w==0) ? kh : (w==1) ? kl : (w==2) ? vth : vtl;
  short* myb = (w==0) ? skh : (w==1) ? skl : (w==2) ? svh : svl;
  bool isv = (w >= 2);
  int rloc = lane >> 3, pch = lane & 7;
  for (int kt = ktb; kt < kte; kt++){
    #pragma unroll
    for (int j = 0; j < 8; j++){
      int r = j*8 + rloc;
      int c = pch ^ (r & 7);
      long ga = isv ? (base + (long)r*1024 + kt*64 + c*8)
                    : (base + (long)(kt*64 + r)*64 + c*8);
      gl_lds16(gsrc + ga, myb + j*512);
    }
    __syncthreads();
    f32x4 sfr[4];
    #pragma unroll
    for (int nt = 0; nt < 4; nt++){
      f32x4 c = (f32x4){0.f,0.f,0.f,0.f};
      int krow = (nt*16 + l15) * 64;
      #pragma unroll
      for (int ch = 0; ch < 2; ch++){
        int pc = ((ch*4 + quad) ^ (l15 & 7)) * 8;
        bf16x8 kfh = *(const bf16x8*)&skh[krow + pc];
        bf16x8 kfl = *(const bf16x8*)&skl[krow + pc];
        c = MFMA16(qfh[ch], kfh, c);
        c = MFMA16(qfh[ch], kfl, c);
        c = MFMA16(qfl[ch], kfh, c);
      }
      sfr[nt] = c;
    }
    if (kt == qt){
      #pragma unroll
      for (int nt = 0; nt < 4; nt++)
        #pragma unroll
        for (int rg = 0; rg < 4; rg++){
          int kp = nt*16 + l15, qp = w*16 + quad*4 + rg;
          if (kp > qp) sfr[nt][rg] = -1e30f;
        }
    }
    float rmax[4];
    #pragma unroll
    for (int rg = 0; rg < 4; rg++)
      rmax[rg] = fmaxf(fmaxf(sfr[0][rg], sfr[1][rg]), fmaxf(sfr[2][rg], sfr[3][rg]));
    #pragma unroll
    for (int xm = 1; xm < 16; xm <<= 1)
      #pragma unroll
      for (int rg = 0; rg < 4; rg++)
        rmax[rg] = fmaxf(rmax[rg], __shfl_xor(rmax[rg], xm, 64));
    float alpha[4];
    #pragma unroll
    for (int rg = 0; rg < 4; rg++){
      float mn = fmaxf(m_i[rg], rmax[rg]);
      alpha[rg] = exp2f(m_i[rg] - mn);
      m_i[rg] = mn;
    }
    float rsum[4] = {0.f,0.f,0.f,0.f};
    #pragma unroll
    for (int nt = 0; nt < 4; nt++)
      #pragma unroll
      for (int rg = 0; rg < 4; rg++){
        float p = exp2f(sfr[nt][rg] - m_i[rg]);
        sfr[nt][rg] = p; rsum[rg] += p;
      }
    #pragma unroll
    for (int xm = 1; xm < 16; xm <<= 1)
      #pragma unroll
      for (int rg = 0; rg < 4; rg++)
        rsum[rg] += __shfl_xor(rsum[rg], xm, 64);
    #pragma unroll
    for (int rg = 0; rg < 4; rg++) l_i[rg] = l_i[rg]*alpha[rg] + rsum[rg];
    #pragma unroll
    for (int hd = 0; hd < 4; hd++)
      #pragma unroll
      for (int rg = 0; rg < 4; rg++) oacc[hd][rg] *= alpha[rg];
    #pragma unroll
    for (int nt = 0; nt < 4; nt++)
      #pragma unroll
      for (int rg = 0; rg < 4; rg++){
        float p = sfr[nt][rg];
        short hv = f2bf(p);
        sph[w][(quad*4+rg)*72 + nt*16 + l15] = hv;
        spl[w][(quad*4+rg)*72 + nt*16 + l15] = f2bf(p - bf2f(hv));
      }
    bf16x8 pfh[2], pfl[2];
    #pragma unroll
    for (int ch = 0; ch < 2; ch++){
      pfh[ch] = *(const bf16x8*)&sph[w][l15*72 + ch*32 + quad*8];
      pfl[ch] = *(const bf16x8*)&spl[w][l15*72 + ch*32 + quad*8];
    }
    #pragma unroll
    for (int hd = 0; hd < 4; hd++){
      int vrow = (hd*16 + l15) * 64;
      #pragma unroll
      for (int ch = 0; ch < 2; ch++){
        int pc = ((ch*4 + quad) ^ (l15 & 7)) * 8;
        bf16x8 vfh = *(const bf16x8*)&svh[vrow + pc];
        bf16x8 vfl = *(const bf16x8*)&svl[vrow + pc];
        oacc[hd] = MFMA16(pfh[ch], vfh, oacc[hd]);
        oacc[hd] = MFMA16(pfh[ch], vfl, oacc[hd]);
        oacc[hd] = MFMA16(pfl[ch], vfh, oacc[hd]);
      }
    }
    __syncthreads();
  }
  long pb = ((long)(half*24 + bh)*1024);
  #pragma unroll
  for (int hdt = 0; hdt < 4; hdt++)
    #pragma unroll
    for (int rg = 0; rg < 4; rg++){
      int qp = q0 + w*16 + quad*4 + rg;
      po[(pb + qp)*64 + hdt*16 + l15] = oacc[hdt][rg];
    }
  if (l15 == 0){
    #pragma unroll
    for (int rg = 0; rg < 4; rg++){
      int qp = q0 + w*16 + quad*4 + rg;
      pm[pb + qp] = m_i[rg];
      pl[pb + qp] = l_i[rg];
    }
  }
}

// ---------------- attention combine: merge 2 partials -> bf16 hi/lo ---------
// log2-domain partials: weights via exp2f.
__global__ void k_attn_combine(const float* __restrict__ po, const float* __restrict__ pm,
                               const float* __restrict__ pl,
                               short* __restrict__ oh, short* __restrict__ ol){
  int bh = blockIdx.y, tid = threadIdx.x;
  int r = blockIdx.x*64 + (tid >> 2);
  int c0 = (tid & 3) * 16;
  long i0 = (long)bh*1024 + r;
  long i1 = (long)(24 + bh)*1024 + r;
  float m0 = pm[i0], m1 = pm[i1], l0 = pl[i0], l1 = pl[i1];
  float m = fmaxf(m0, m1);
  float a0 = exp2f(m0 - m), a1 = exp2f(m1 - m);
  float inv = 1.f / (a0*l0 + a1*l1);
  a0 *= inv; a1 *= inv;
  int b = bh / 12, hh = bh % 12;
  long ob = ((long)(b*1024 + r))*768 + hh*64 + c0;
  short hv[16], lv[16];
  #pragma unroll
  for (int j = 0; j < 4; j++){
    float4 o0 = *(const float4*)&po[i0*64 + c0 + j*4];
    float4 o1 = *(const float4*)&po[i1*64 + c0 + j*4];
    float vs[4] = {a0*o0.x + a1*o1.x, a0*o0.y + a1*o1.y,
                   a0*o0.z + a1*o1.z, a0*o0.w + a1*o1.w};
    #pragma unroll
    for (int q = 0; q < 4; q++){
      short h = f2bf(vs[q]);
      hv[j*4+q] = h; lv[j*4+q] = f2bf(vs[q] - bf2f(h));
    }
  }
  *(bf16x8*)(oh + ob)     = *(bf16x8*)&hv[0];
  *(bf16x8*)(oh + ob + 8) = *(bf16x8*)&hv[8];
  *(bf16x8*)(ol + ob)     = *(bf16x8*)&lv[0];
  *(bf16x8*)(ol + ob + 8) = *(bf16x8*)&lv[8];
}

// ---------------- split GEMM Wo -> partials, BM=64 BN=128, split-K=2 --------
// grid (32,6,2) = 384 blocks = 1.5/CU. Partials fp32; combine fused into
// k_ln2router.
__global__ __launch_bounds__(256,3) void k_wo(
    const short* __restrict__ Ah, const short* __restrict__ Al,
    const short* __restrict__ Bh, const short* __restrict__ Bl,
    float* __restrict__ p0, float* __restrict__ p1){
  int M0 = blockIdx.x * 64, N0 = blockIdx.y * 128;
  int ks = blockIdx.z;
  int kbeg = ks * 384;
  float* wp = ks ? p1 : p0;
  __shared__ __align__(16) short lah[64*64], lal[64*64], lbh[128*64], lbl[128*64];
  int tid = threadIdx.x;
  int w = tid >> 6, lane = tid & 63, l15 = lane & 15, quad = lane >> 4;
  int mbase = (w & 1) * 32, nbase = (w >> 1) * 64;
  f32x4 acc[2][4];
  #pragma unroll
  for (int i = 0; i < 2; i++)
    #pragma unroll
    for (int j = 0; j < 4; j++) acc[i][j] = (f32x4){0.f,0.f,0.f,0.f};
  int rl = lane >> 3, pch = lane & 7;
  long gA[2], gB[4];
  #pragma unroll
  for (int j = 0; j < 2; j++){
    int r = w*16 + j*8 + rl;
    int c = pch ^ (r & 7);
    gA[j] = (long)(M0 + r)*768 + kbeg + c*8;
  }
  #pragma unroll
  for (int j = 0; j < 4; j++){
    int r = w*32 + j*8 + rl;
    int c = pch ^ (r & 7);
    gB[j] = (long)(N0 + r)*768 + kbeg + c*8;
  }
  for (int k0 = 0; k0 < 384; k0 += 64){
    #pragma unroll
    for (int j = 0; j < 2; j++){
      gl_lds16(Ah + gA[j] + k0, lah + w*1024 + j*512);
      gl_lds16(Al + gA[j] + k0, lal + w*1024 + j*512);
    }
    #pragma unroll
    for (int j = 0; j < 4; j++){
      gl_lds16(Bh + gB[j] + k0, lbh + w*2048 + j*512);
      gl_lds16(Bl + gB[j] + k0, lbl + w*2048 + j*512);
    }
    __syncthreads();
    #pragma unroll
    for (int kk = 0; kk < 2; kk++){
      int swq = ((kk*4 + quad) ^ (l15 & 7)) * 8;
      bf16x8 afh[2], afl[2];
      #pragma unroll
      for (int mt = 0; mt < 2; mt++){
        afh[mt] = *(const bf16x8*)&lah[(mbase+mt*16+l15)*64 + swq];
        afl[mt] = *(const bf16x8*)&lal[(mbase+mt*16+l15)*64 + swq];
      }
      #pragma unroll
      for (int nt = 0; nt < 4; nt++){
        bf16x8 bfh = *(const bf16x8*)&lbh[(nbase+nt*16+l15)*64 + swq];
        bf16x8 bfl = *(const bf16x8*)&lbl[(nbase+nt*16+l15)*64 + swq];
        #pragma unroll
        for (int mt = 0; mt < 2; mt++){
          acc[mt][nt] = MFMA16(afh[mt], bfh, acc[mt][nt]);
          acc[mt][nt] = MFMA16(afh[mt], bfl, acc[mt][nt]);
          acc[mt][nt] = MFMA16(afl[mt], bfh, acc[mt][nt]);
        }
      }
    }
    __syncthreads();
  }
  #pragma unroll
  for (int mt = 0; mt < 2; mt++)
    #pragma unroll
    for (int nt = 0; nt < 4; nt++)
      #pragma unroll
      for (int rg = 0; rg < 4; rg++){
        int m = M0 + mbase + mt*16 + quad*4 + rg;
        int n = N0 + nbase + nt*16 + l15;
        wp[(long)m*768 + n] = acc[mt][nt][rg];
      }
}

// ---------------- fused: h = P0+P1+x+bo; LN2; router (no global atomics) ----
// grid 256 x 256thr; wave wv handles tokens wv*2, wv*2+1. Vectorized float4.
__global__ void k_ln2router(const float* __restrict__ p0, const float* __restrict__ p1,
                            const float* __restrict__ x, const float* __restrict__ bo,
                            const float* __restrict__ g, const float* __restrict__ bb,
                            const float* __restrict__ Wr, const float* __restrict__ br,
                            float* __restrict__ hout, short* __restrict__ xn2,
                            int* __restrict__ sel, float* __restrict__ gw){
  int wv = (blockIdx.x*256 + threadIdx.x) >> 6;
  int lane = threadIdx.x & 63;
  #pragma unroll
  for (int rep = 0; rep < 2; rep++){
    int t = wv*2 + rep;
    float4 hv[3];
    #pragma unroll
    for (int j = 0; j < 3; j++){
      long i = (long)t*192 + j*64 + lane;
      float4 a  = ((const float4*)p0)[i];
      float4 b  = ((const float4*)p1)[i];
      float4 xx = ((const float4*)x)[i];
      float4 bv = ((const float4*)bo)[j*64 + lane];
      float4 h;
      h.x = a.x + b.x + xx.x + bv.x;
      h.y = a.y + b.y + xx.y + bv.y;
      h.z = a.z + b.z + xx.z + bv.z;
      h.w = a.w + b.w + xx.w + bv.w;
      ((float4*)hout)[i] = h;
      hv[j] = h;
    }
    float s = 0.f, q = 0.f;
    #pragma unroll
    for (int j = 0; j < 3; j++){
      s += hv[j].x + hv[j].y + hv[j].z + hv[j].w;
      q += hv[j].x*hv[j].x + hv[j].y*hv[j].y + hv[j].z*hv[j].z + hv[j].w*hv[j].w;
    }
    #pragma unroll
    for (int xm = 1; xm < 64; xm <<= 1){ s += __shfl_xor(s, xm, 64); q += __shfl_xor(q, xm, 64); }
    float mean = s * (1.f/768.f);
    float var  = q * (1.f/768.f) - mean*mean;
    float inv  = 1.f / sqrtf(var + 1e-5f);
    float part[8] = {0,0,0,0,0,0,0,0};
    #pragma unroll
    for (int j = 0; j < 3; j++){
      int d0 = (j*64 + lane) * 4;
      float4 gv = ((const float4*)g)[j*64 + lane];
      float4 bbv = ((const float4*)bb)[j*64 + lane];
      float xn0 = (hv[j].x - mean)*inv*gv.x + bbv.x;
      float xn1 = (hv[j].y - mean)*inv*gv.y + bbv.y;
      float xn2v = (hv[j].z - mean)*inv*gv.z + bbv.z;
      float xn3 = (hv[j].w - mean)*inv*gv.w + bbv.w;
      bf16x4 pk = (bf16x4){f2bf(xn0), f2bf(xn1), f2bf(xn2v), f2bf(xn3)};
      *(bf16x4*)&xn2[(long)t*768 + d0] = pk;
      #pragma unroll
      for (int e = 0; e < 8; e++){
        part[e] += xn0 * Wr[(d0+0)*8 + e];
        part[e] += xn1 * Wr[(d0+1)*8 + e];
        part[e] += xn2v * Wr[(d0+2)*8 + e];
        part[e] += xn3 * Wr[(d0+3)*8 + e];
      }
    }
    #pragma unroll
    for (int xm = 1; xm < 64; xm <<= 1)
      #pragma unroll
      for (int e = 0; e < 8; e++) part[e] += __shfl_xor(part[e], xm, 64);
    if (lane == 0){
      float lg[8];
      #pragma unroll
      for (int e = 0; e < 8; e++) lg[e] = part[e] + br[e];
      int i1 = 0;
      for (int e = 1; e < 8; e++) if (lg[e] > lg[i1]) i1 = e;
      int i2 = -1;
      for (int e = 0; e < 8; e++){ if (e == i1) continue; if (i2 < 0 || lg[e] > lg[i2]) i2 = e; }
      float e2 = expf(lg[i2] - lg[i1]);
      float is = 1.f / (1.f + e2);
      gw[t*2]   = is;
      gw[t*2+1] = e2 * is;
      sel[t*2]   = i1;
      sel[t*2+1] = i2;
    }
  }
}

// single-block compaction: wave-aggregated ballot histogram + placement.
__global__ void k_build(const int* __restrict__ sel, int* __restrict__ poffs,
                        int* __restrict__ mbc, int* __restrict__ ptot,
                        int* __restrict__ pperm, int* __restrict__ inv){
  __shared__ int cnt8[8], cur[8], wbase[16][8];
  int tid = threadIdx.x;   // 1024
  int lane = tid & 63, wv = tid >> 6;
  if (tid < 8) cnt8[tid] = 0;
  __syncthreads();
  int sv[4];
  #pragma unroll
  for (int r = 0; r < 4; r++){
    sv[r] = sel[tid + r*1024];
    #pragma unroll
    for (int e = 0; e < 8; e++){
      unsigned long long mk = __ballot(sv[r] == e);
      if (lane == 0) atomicAdd(&cnt8[e], (int)__popcll(mk));
    }
  }
  __syncthreads();
  if (tid == 0){
    int p = 0;
    for (int e = 0; e < 8; e++){
      cur[e] = p; poffs[e] = p;
      int pc = (cnt8[e] + 127) & ~127;
      mbc[e] = pc >> 7;
      p += pc;
    }
    *ptot = p;
  }
  __syncthreads();
  #pragma unroll
  for (int r = 0; r < 5; r++) pperm[tid + r*1024] = -1;
  __syncthreads();
  unsigned long long lmask = (1ull << lane) - 1ull;
  #pragma unroll
  for (int r = 0; r < 4; r++){
    int s = sv[r];
    unsigned long long mk[8];
    #pragma unroll
    for (int e = 0; e < 8; e++) mk[e] = __ballot(s == e);
    if (lane == 0){
      #pragma unroll
      for (int e = 0; e < 8; e++)
        wbase[wv][e] = atomicAdd(&cur[e], (int)__popcll(mk[e]));
    }
    unsigned long long mks = 0;
    #pragma unroll
    for (int e = 0; e < 8; e++) if (s == e) mks = mk[e];   // static indexing (rule #20)
    int pos = wbase[wv][s] + (int)__popcll(mks & lmask);
    int i = tid + r*1024;
    pperm[pos] = i;
    inv[i] = pos;
  }
}

// ---------------- MoE GEMM1: h1[p] = gelu(xn2[tok(p)] @ W1T[e] + b1) --------
// grid (192 = e*24+n weight-tile [XCD-pinned], 16 = Mblk-within-expert)
// Round-1 proven config: single-buffer, 2 barriers/K-step, 3 blocks/CU.
__global__ __launch_bounds__(256,3) void k_moe1(
    const short* __restrict__ xn2, const short* __restrict__ W1T,
    const float* __restrict__ b1,
    const int* __restrict__ poffs, const int* __restrict__ mbc,
    const int* __restrict__ pperm, short* __restrict__ h1){
  int t = blockIdx.x;
  int e = t / 24, n = t % 24;
  if ((int)blockIdx.y >= mbc[e]) return;
  int M0 = poffs[e] + blockIdx.y * 128;
  int N0 = n * 128;
  const short* Bp = W1T + (long)e * 3072 * 768;
  __shared__ __align__(16) short la[128*64], lb[128*64];
  __shared__ int rtok[128];
  int tid = threadIdx.x, w = tid >> 6, lane = tid & 63, l15 = lane & 15, quad = lane >> 4;
  if (tid < 128) rtok[tid] = pperm[M0 + tid];
  __syncthreads();
  int rl = lane >> 3, pch = lane & 7;
  long gA[4], gB[4];
  #pragma unroll
  for (int j = 0; j < 4; j++){
    int r = w*32 + j*8 + rl;
    int c = pch ^ (r & 7);
    int tk = rtok[r]; tk = (tk >= 0) ? (tk >> 1) : 0;
    gA[j] = (long)tk*768 + c*8;
    gB[j] = (long)(N0 + r)*768 + c*8;
  }
  short* ldA = la + w*2048;
  short* ldB = lb + w*2048;
  f32x4 acc[4][4];
  #pragma unroll
  for (int i = 0; i < 4; i++)
    #pragma unroll
    for (int j = 0; j < 4; j++) acc[i][j] = (f32x4){0.f,0.f,0.f,0.f};
  int mbase = (w & 1) * 64, nbase = (w >> 1) * 64;
  for (int k0 = 0; k0 < 768; k0 += 64){
    #pragma unroll
    for (int j = 0; j < 4; j++) gl_lds16(xn2 + gA[j] + k0, ldA + j*512);
    #pragma unroll
    for (int j = 0; j < 4; j++) gl_lds16(Bp  + gB[j] + k0, ldB + j*512);
    __syncthreads();
    #pragma unroll
    for (int kk = 0; kk < 2; kk++){
      int swq = ((kk*4 + quad) ^ (l15 & 7)) * 8;
      bf16x8 af[4];
      #pragma unroll
      for (int mt = 0; mt < 4; mt++)
        af[mt] = *(const bf16x8*)&la[(mbase+mt*16+l15)*64 + swq];
      #pragma unroll
      for (int nt = 0; nt < 4; nt++){
        bf16x8 bf = *(const bf16x8*)&lb[(nbase+nt*16+l15)*64 + swq];
        #pragma unroll
        for (int mt = 0; mt < 4; mt++) acc[mt][nt] = MFMA16(af[mt], bf, acc[mt][nt]);
      }
    }
    __syncthreads();
  }
  #pragma unroll
  for (int mt = 0; mt < 4; mt++)
    #pragma unroll
    for (int nt = 0; nt < 4; nt++)
      #pragma unroll
      for (int rg = 0; rg < 4; rg++){
        int ml = mbase + mt*16 + quad*4 + rg;
        if (rtok[ml] >= 0){
          int nn = N0 + nbase + nt*16 + l15;
          float vv = acc[mt][nt][rg] + b1[e*3072 + nn];
          float gl = 0.5f * vv * (1.f + erff(vv * 0.70710678118654752f));
          h1[(long)(M0 + ml)*3072 + nn] = f2bf(gl);
        }
      }
}

// ---------------- MoE GEMM2: E[ks][slot] = h1 @ W2T[e](+b2), split-K=4 ------
// grid (192 = e*24 + n*4 + ks weight-tile, 16 = Mblk-within-expert)
// Round-1 proven config (reverted from the round-8 counted-vmcnt experiment:
// that run's CONTROL kernel regressed 57% -> confounded environment; and the
// 64KB-LDS occupancy cost is a proven regression on this structure).
__global__ __launch_bounds__(256,4) void k_moe2(
    const short* __restrict__ h1, const short* __restrict__ W2T,
    const float* __restrict__ b2,
    const int* __restrict__ poffs, const int* __restrict__ mbc,
    float* __restrict__ e0, float* __restrict__ e1,
    float* __restrict__ e2, float* __restrict__ e3){
  int t = blockIdx.x;
  int e = t / 24, r24 = t % 24;
  int n = r24 >> 2, ks = r24 & 3;
  if ((int)blockIdx.y >= mbc[e]) return;
  int M0 = poffs[e] + blockIdx.y * 128;
  int N0 = n * 128;
  int kbeg = ks * 768;
  const short* Bp = W2T + (long)e * 768 * 3072;
  float* eo = (ks == 0) ? e0 : (ks == 1) ? e1 : (ks == 2) ? e2 : e3;
  __shared__ __align__(16) short la[128*64], lb[128*64];
  int tid = threadIdx.x, w = tid >> 6, lane = tid & 63, l15 = lane & 15, quad = lane >> 4;
  int rl = lane >> 3, pch = lane & 7;
  long gA[4], gB[4];
  #pragma unroll
  for (int j = 0; j < 4; j++){
    int r = w*32 + j*8 + rl;
    int c = pch ^ (r & 7);
    gA[j] = (long)(M0 + r)*3072 + kbeg + c*8;
    gB[j] = (long)(N0 + r)*3072 + kbeg + c*8;
  }
  short* ldA = la + w*2048;
  short* ldB = lb + w*2048;
  f32x4 acc[4][4];
  #pragma unroll
  for (int i = 0; i < 4; i++)
    #pragma unroll
    for (int j = 0; j < 4; j++) acc[i][j] = (f32x4){0.f,0.f,0.f,0.f};
  int mbase = (w & 1) * 64, nbase = (w >> 1) * 64;
  for (int k0 = 0; k0 < 768; k0 += 64){
    #pragma unroll
    for (int j = 0; j < 4; j++) gl_lds16(h1 + gA[j] + k0, ldA + j*512);
    #pragma unroll
    for (int j = 0; j < 4; j++) gl_lds16(Bp + gB[j] + k0, ldB + j*512);
    __syncthreads();
    #pragma unroll
    for (int kk = 0; kk < 2; kk++){
      int swq = ((kk*4 + quad) ^ (l15 & 7)) * 8;
      bf16x8 af[4];
      #pragma unroll
      for (int mt = 0; mt < 4; mt++)
        af[mt] = *(const bf16x8*)&la[(mbase+mt*16+l15)*64 + swq];
      #pragma unroll
      for (int nt = 0; nt < 4; nt++){
        bf16x8 bf = *(const bf16x8*)&lb[(nbase+nt*16+l15)*64 + swq];
        #pragma unroll
        for (int mt = 0; mt < 4; mt++) acc[mt][nt] = MFMA16(af[mt], bf, acc[mt][nt]);
      }
    }
    __syncthreads();
  }
  #pragma unroll
  for (int mt = 0; mt < 4; mt++)
    #pragma unroll
    for (int nt = 0; nt < 4; nt++)
      #pragma unroll
      for (int rg = 0; rg < 4; rg++){
        int ml = mbase + mt*16 + quad*4 + rg;
        int nn = N0 + nbase + nt*16 + l15;
        float vv = acc[mt][nt][rg] + ((ks == 0) ? b2[e*768 + nn] : 0.f);
        eo[(long)(M0 + ml)*768 + nn] = vv;
      }
}

// ---------------- final combine: out = h + Σ_slot g*(E0+E1+E2+E3)[slot] -----
__global__ void k_combine(const float* __restrict__ h,
                          const float* __restrict__ e0, const float* __restrict__ e1,
                          const float* __restrict__ e2, const float* __restrict__ e3,
                          const int* __restrict__ inv, const float* __restrict__ gw,
                          float* __restrict__ out){
  int i = blockIdx.x * 256 + threadIdx.x;     // 393216 float4s
  int t = i / 192, c = i - t * 192;
  int s0 = inv[2*t], s1 = inv[2*t+1];
  float g0 = gw[2*t], g1 = gw[2*t+1];
  float4 a  = ((const float4*)h)[i];
  long o0 = (long)s0*192 + c, o1 = (long)s1*192 + c;
  float4 x0 = ((const float4*)e0)[o0];
  float4 y0 = ((const float4*)e1)[o0];
  float4 z0 = ((const float4*)e2)[o0];
  float4 w0 = ((const float4*)e3)[o0];
  float4 x1 = ((const float4*)e0)[o1];
  float4 y1 = ((const float4*)e1)[o1];
  float4 z1 = ((const float4*)e2)[o1];
  float4 w1 = ((const float4*)e3)[o1];
  float4 o;
  o.x = a.x + g0*(x0.x + y0.x + z0.x + w0.x) + g1*(x1.x + y1.x + z1.x + w1.x);
  o.y = a.y + g0*(x0.y + y0.y + z0.y + w0.y) + g1*(x1.y + y1.y + z1.y + w1.y);
  o.z = a.z + g0*(x0.z + y0.z + z0.z + w0.z) + g1*(x1.z + y1.z + z1.z + w1.z);
  o.w = a.w + g0*(x0.w + y0.w + z0.w + w0.w) + g1*(x1.w + y1.w + z1.w + w1.w);
  ((float4*)out)[i] = o;
}

// ---------------- launcher ----------------
extern "C" void kernel_launch(void* const* d_in, const int* in_sizes, int n_in,
                              void* d_out, int out_size, void* d_ws, size_t ws_size,
                              hipStream_t stream){
  const float* x    = (const float*)d_in[0];
  const float* ln1g = (const float*)d_in[1];
  const float* ln1b = (const float*)d_in[2];
  const float* Wq   = (const float*)d_in[3];
  const float* Wk   = (const float*)d_in[4];
  const float* Wv   = (const float*)d_in[5];
  const float* Wo   = (const float*)d_in[6];
  const float* bo   = (const float*)d_in[7];
  const float* ln2g = (const float*)d_in[8];
  const float* ln2b = (const float*)d_in[9];
  const float* Wr   = (const float*)d_in[10];
  const float* br   = (const float*)d_in[11];
  const float* W1   = (const float*)d_in[12];
  const float* b1   = (const float*)d_in[13];
  const float* W2   = (const float*)d_in[14];
  const float* b2   = (const float*)d_in[15];

  char* ws = (char*)d_ws;
  size_t off = 0;
  auto alloc = [&](size_t bytes) -> void* {
    void* p = ws + off;
    off += (bytes + 255) & ~(size_t)255;
    return p;
  };
  short* WQKVH = (short*)alloc(2304l*768*2);
  short* WQKVL = (short*)alloc(2304l*768*2);
  short* WOH   = (short*)alloc(768l*768*2);
  short* WOL   = (short*)alloc(768l*768*2);
  short* W1T   = (short*)alloc(8l*3072*768*2);
  short* W2T   = (short*)alloc(8l*768*3072*2);
  short* XN1H  = (short*)alloc(2048l*768*2);
  short* XN1L  = (short*)alloc(2048l*768*2);
  short* QH    = (short*)alloc(2048l*768*2);
  short* QL    = (short*)alloc(2048l*768*2);
  short* KH    = (short*)alloc(2048l*768*2);
  short* KL    = (short*)alloc(2048l*768*2);
  short* VTH   = (short*)alloc(2048l*768*2);
  short* VTL   = (short*)alloc(2048l*768*2);
  short* ATH   = (short*)alloc(2048l*768*2);
  short* ATL   = (short*)alloc(2048l*768*2);
  float* HBUF  = (float*)alloc(2048l*768*4);
  short* XN2   = (short*)alloc(2048l*768*2);
  short* H1    = (short*)alloc(5120l*3072*2);
  float* E0    = (float*)alloc(5120l*768*4);
  float* E1    = (float*)alloc(5120l*768*4);
  float* PO    = (float*)alloc(2l*24*1024*64*4);
  float* PM    = (float*)alloc(2l*24*1024*4);
  float* PL    = (float*)alloc(2l*24*1024*4);
  int*   POFF  = (int*)alloc(8*4);
  int*   MBC   = (int*)alloc(8*4);
  int*   PTOT  = (int*)alloc(4);
  int*   SEL   = (int*)alloc(4096*4);
  int*   PPERM = (int*)alloc(5120*4);
  int*   INV   = (int*)alloc(4096*4);
  float* GW    = (float*)alloc(4096*4);
  (void)ws_size; (void)in_sizes; (void)n_in; (void)out_size;

  // E2/E3: alias the attention-path buffers (XN1H..ATL = 10 x 3,145,728 B
  // = exactly 2 x 5120*768*4 B). All consumers of that region (k_qkv,
  // k_attn, k_wo) complete before k_moe2 runs on the same stream.
  float* E2 = (float*)XN1H;
  float* E3 = E2 + 5120l*768;
  // WP0/WP1: alias PO (12.58 MB = exactly 2 x 2048*768*4). k_attn_combine
  // (PO's last consumer) completes before k_wo writes on the same stream.
  float* WP0 = PO;
  float* WP1 = PO + 2048l*768;

  // weight prep: 4 square transposes in ONE launch; W1/W2 separate
  k_transpose4<<<dim3(12,12,4),256,0,stream>>>(
      Wq, Wk, Wv, Wo,
      WQKVH,             WQKVL,
      WQKVH + 768l*768,  WQKVL + 768l*768,
      WQKVH + 1536l*768, WQKVL + 1536l*768,
      WOH, WOL);
  k_transpose<<<dim3(48,12,8),256,0,stream>>>(W1, 768l*3072, W1T, nullptr, 3072l*768, 768, 3072);
  k_transpose<<<dim3(12,48,8),256,0,stream>>>(W2, 3072l*768, W2T, nullptr, 768l*3072, 3072, 768);

  // attention path (split-bf16 precision)
  k_ln1<<<2048,256,0,stream>>>(x, ln1g, ln1b, XN1H, XN1L);
  k_qkv<<<dim3(32,18),256,0,stream>>>(XN1H, XN1L, WQKVH, WQKVL, QH, QL, KH, KL, VTH, VTL);
  k_attn<<<dim3(32,24),256,0,stream>>>(QH, QL, KH, KL, VTH, VTL, PO, PM, PL);
  k_attn_combine<<<dim3(16,24),256,0,stream>>>(PO, PM, PL, ATH, ATL);
  k_wo<<<dim3(32,6,2),256,0,stream>>>(ATH, ATL, WOH, WOL, WP0, WP1);

  // fused residual+LN2+router, then MoE (no global atomics)
  k_ln2router<<<256,256,0,stream>>>(WP0, WP1, x, bo, ln2g, ln2b, Wr, br,
                                    HBUF, XN2, SEL, GW);
  k_build<<<1,1024,0,stream>>>(SEL, POFF, MBC, PTOT, PPERM, INV);
  k_moe1<<<dim3(192,16),256,0,stream>>>(XN2, W1T, b1, POFF, MBC, PPERM, H1);
  k_moe2<<<dim3(192,16),256,0,stream>>>(H1, W2T, b2, POFF, MBC, E0, E1, E2, E3);
  k_combine<<<1536,256,0,stream>>>(HBUF, E0, E1, E2, E3, INV, GW, (float*)d_out);
}

// Round 10
// 425.692 us; speedup vs baseline: 1.2052x; 1.0228x over previous
//
#include <hip/hip_runtime.h>

// ---------------- common helpers ----------------
using bf16x8 = __attribute__((ext_vector_type(8))) short;
using bf16x4 = __attribute__((ext_vector_type(4))) short;
using f32x4  = __attribute__((ext_vector_type(4))) float;

#define DEV __device__ __forceinline__

DEV short f2bf(float x){
  unsigned u = __float_as_uint(x);
  u += 0x7fffu + ((u >> 16) & 1u);
  return (short)(u >> 16);
}
DEV float bf2f(short h){ return __uint_as_float(((unsigned)(unsigned short)h) << 16); }

#define MFMA16(a,b,c) __builtin_amdgcn_mfma_f32_16x16x32_bf16(a,b,c,0,0,0)

// async global->LDS, 16B per lane; LDS dest is wave-uniform base + lane*16
DEV void gl_lds16(const void* g, void* l){
  __builtin_amdgcn_global_load_lds(
      (const __attribute__((address_space(1))) unsigned*)g,
      (__attribute__((address_space(3))) unsigned*)l, 16, 0, 0);
}

// Problem constants: B=2 S=1024 D=768 H=12 HD=64 E=8 DF=3072 K=2, T=2048

// ---------------- fused prep: ALL weight transposes + LN1 in ONE launch -----
// blocks [0,576):     4x 768x768 square transpose (hi/lo)  [z=b/144]
// blocks [576,5184):  W1 transpose  (48x12 x 8 experts)
// blocks [5184,9792): W2 transpose  (12x48 x 8 experts)
// blocks [9792,11840): LN1 token t = b-9792
// Roles are blockIdx-uniform (no divergence); mutual independence lets the
// small kernels co-schedule with the big transposes (saves 3 launches + tail).
__global__ void k_prep(const float* __restrict__ Wq, const float* __restrict__ Wk,
                       const float* __restrict__ Wv, const float* __restrict__ Wo,
                       short* __restrict__ WQKVH, short* __restrict__ WQKVL,
                       short* __restrict__ WOH, short* __restrict__ WOL,
                       const float* __restrict__ W1, short* __restrict__ W1T,
                       const float* __restrict__ W2, short* __restrict__ W2T,
                       const float* __restrict__ x, const float* __restrict__ ln1g,
                       const float* __restrict__ ln1b,
                       short* __restrict__ XN1H, short* __restrict__ XN1L){
  __shared__ float tile[64][65];
  __shared__ float ss[4], qs[4];
  int b = blockIdx.x;
  if (b >= 9792){
    // ---- LN1: x -> xn1 hi/lo bf16 ----
    int t = b - 9792, tid = threadIdx.x;
    const float* xr = x + (long)t * 768;
    float v[3];
    #pragma unroll
    for (int j = 0; j < 3; j++) v[j] = xr[tid + 256*j];
    float s = v[0]+v[1]+v[2];
    float q = v[0]*v[0]+v[1]*v[1]+v[2]*v[2];
    #pragma unroll
    for (int o = 32; o > 0; o >>= 1){ s += __shfl_down(s,o,64); q += __shfl_down(q,o,64); }
    int w = tid >> 6;
    if ((tid & 63) == 0){ ss[w] = s; qs[w] = q; }
    __syncthreads();
    float St = ss[0]+ss[1]+ss[2]+ss[3], Qt = qs[0]+qs[1]+qs[2]+qs[3];
    float mean = St * (1.f/768.f);
    float var  = Qt * (1.f/768.f) - mean*mean;
    float inv  = 1.f / sqrtf(var + 1e-5f);
    #pragma unroll
    for (int j = 0; j < 3; j++){
      int d = tid + 256*j;
      float xn = (v[j]-mean)*inv*ln1g[d] + ln1b[d];
      short hv = f2bf(xn);
      XN1H[(long)t*768 + d] = hv;
      XN1L[(long)t*768 + d] = f2bf(xn - bf2f(hv));
    }
    return;
  }
  // ---- transpose roles ----
  const float* src; short* dhi; short* dlo; int R, C, xx, yy;
  if (b < 576){
    int zz = b / 144, rem = b % 144; xx = rem % 12; yy = rem / 12;
    src = (zz==0) ? Wq : (zz==1) ? Wk : (zz==2) ? Wv : Wo;
    dhi = (zz==0) ? WQKVH : (zz==1) ? WQKVH + 768l*768 : (zz==2) ? WQKVH + 1536l*768 : WOH;
    dlo = (zz==0) ? WQKVL : (zz==1) ? WQKVL + 768l*768 : (zz==2) ? WQKVL + 1536l*768 : WOL;
    R = 768; C = 768;
  } else if (b < 5184){
    int i = b - 576, zz = i / 576, rem = i % 576; xx = rem % 48; yy = rem / 48;
    src = W1 + (long)zz * 768 * 3072;
    dhi = W1T + (long)zz * 3072 * 768;
    dlo = nullptr;
    R = 768; C = 3072;
  } else {
    int i = b - 5184, zz = i / 576, rem = i % 576; xx = rem % 12; yy = rem / 12;
    src = W2 + (long)zz * 3072 * 768;
    dhi = W2T + (long)zz * 768 * 3072;
    dlo = nullptr;
    R = 3072; C = 768;
  }
  int c0 = xx * 64, r0 = yy * 64;
  int tx = threadIdx.x & 15, ty = threadIdx.x >> 4;   // 16 col-quads x 16 rows
  #pragma unroll
  for (int i = 0; i < 4; i++){
    int r = ty + 16*i;
    float4 v = *(const float4*)&src[(long)(r0 + r) * C + c0 + tx*4];
    tile[r][tx*4+0] = v.x; tile[r][tx*4+1] = v.y;
    tile[r][tx*4+2] = v.z; tile[r][tx*4+3] = v.w;
  }
  __syncthreads();
  int rseg = (threadIdx.x & 7) * 8;                   // 8-row segment
  #pragma unroll
  for (int p = 0; p < 2; p++){
    int col = (threadIdx.x >> 3) + 32*p;              // 32 cols per pass
    short hv[8], lv[8];
    #pragma unroll
    for (int k = 0; k < 8; k++){
      float v = tile[rseg + k][col];
      hv[k] = f2bf(v);
      lv[k] = f2bf(v - bf2f(hv[k]));
    }
    long o = (long)(c0 + col) * R + r0 + rseg;
    *(bf16x8*)&dhi[o] = *(bf16x8*)&hv[0];
    if (dlo) *(bf16x8*)&dlo[o] = *(bf16x8*)&lv[0];
  }
}

// ---------------- split-bf16 GEMM: qkv = xn1 @ Wqkv -------------------------
// BM=64 BN=128: grid (32,18) = 576 blocks = 2.25/CU. LDS 48KB -> 3 blocks/CU.
__global__ __launch_bounds__(256,3) void k_qkv(
    const short* __restrict__ Ah, const short* __restrict__ Al,
    const short* __restrict__ Bh, const short* __restrict__ Bl,
    short* __restrict__ qh, short* __restrict__ ql,
    short* __restrict__ kh, short* __restrict__ kl,
    short* __restrict__ vh, short* __restrict__ vl){
  int M0 = blockIdx.x * 64, N0 = blockIdx.y * 128;
  __shared__ __align__(16) short lah[64*64], lal[64*64], lbh[128*64], lbl[128*64];
  int tid = threadIdx.x;
  int w = tid >> 6, lane = tid & 63, l15 = lane & 15, quad = lane >> 4;
  int mbase = (w & 1) * 32, nbase = (w >> 1) * 64;
  f32x4 acc[2][4];
  #pragma unroll
  for (int i = 0; i < 2; i++)
    #pragma unroll
    for (int j = 0; j < 4; j++) acc[i][j] = (f32x4){0.f,0.f,0.f,0.f};
  int rl = lane >> 3, pch = lane & 7;
  long gA[2], gB[4];
  #pragma unroll
  for (int j = 0; j < 2; j++){
    int r = w*16 + j*8 + rl;
    int c = pch ^ (r & 7);
    gA[j] = (long)(M0 + r)*768 + c*8;
  }
  #pragma unroll
  for (int j = 0; j < 4; j++){
    int r = w*32 + j*8 + rl;
    int c = pch ^ (r & 7);
    gB[j] = (long)(N0 + r)*768 + c*8;
  }
  for (int k0 = 0; k0 < 768; k0 += 64){
    #pragma unroll
    for (int j = 0; j < 2; j++){
      gl_lds16(Ah + gA[j] + k0, lah + w*1024 + j*512);
      gl_lds16(Al + gA[j] + k0, lal + w*1024 + j*512);
    }
    #pragma unroll
    for (int j = 0; j < 4; j++){
      gl_lds16(Bh + gB[j] + k0, lbh + w*2048 + j*512);
      gl_lds16(Bl + gB[j] + k0, lbl + w*2048 + j*512);
    }
    __syncthreads();
    #pragma unroll
    for (int kk = 0; kk < 2; kk++){
      int swq = ((kk*4 + quad) ^ (l15 & 7)) * 8;
      bf16x8 afh[2], afl[2];
      #pragma unroll
      for (int mt = 0; mt < 2; mt++){
        afh[mt] = *(const bf16x8*)&lah[(mbase+mt*16+l15)*64 + swq];
        afl[mt] = *(const bf16x8*)&lal[(mbase+mt*16+l15)*64 + swq];
      }
      #pragma unroll
      for (int nt = 0; nt < 4; nt++){
        bf16x8 bfh = *(const bf16x8*)&lbh[(nbase+nt*16+l15)*64 + swq];
        bf16x8 bfl = *(const bf16x8*)&lbl[(nbase+nt*16+l15)*64 + swq];
        #pragma unroll
        for (int mt = 0; mt < 2; mt++){
          acc[mt][nt] = MFMA16(afh[mt], bfh, acc[mt][nt]);
          acc[mt][nt] = MFMA16(afh[mt], bfl, acc[mt][nt]);
          acc[mt][nt] = MFMA16(afl[mt], bfh, acc[mt][nt]);
        }
      }
    }
    __syncthreads();
  }
  // epilogue: scatter into q[bh][s][hd], k[bh][s][hd], vT[bh][hd][s]
  // Q folds 1/sqrt(HD) * log2(e): softmax runs in log2 domain (exp2f).
  #pragma unroll
  for (int mt = 0; mt < 2; mt++){
    #pragma unroll
    for (int nt = 0; nt < 4; nt++){
      #pragma unroll
      for (int rg = 0; rg < 4; rg++){
        int m = M0 + mbase + mt*16 + quad*4 + rg;
        int n = N0 + nbase + nt*16 + l15;
        float vv = acc[mt][nt][rg];
        int bi = m >> 10, si = m & 1023;
        if (n < 768){
          float sv = vv * 0.18033688011112042f;   // 0.125 * log2(e)
          short hv = f2bf(sv);
          int hh = n >> 6, hd = n & 63;
          long o = (((long)(bi*12+hh)*1024) + si)*64 + hd;
          qh[o] = hv; ql[o] = f2bf(sv - bf2f(hv));
        } else if (n < 1536){
          int n2 = n - 768;
          short hv = f2bf(vv);
          int hh = n2 >> 6, hd = n2 & 63;
          long o = (((long)(bi*12+hh)*1024) + si)*64 + hd;
          kh[o] = hv; kl[o] = f2bf(vv - bf2f(hv));
        } else {
          int n2 = n - 1536;
          short hv = f2bf(vv);
          int hh = n2 >> 6, hd = n2 & 63;
          long o = (((long)(bi*12+hh)*64) + hd)*1024 + si;
          vh[o] = hv; vl[o] = f2bf(vv - bf2f(hv));
        }
      }
    }
  }
}

// ---------------- flash attention, split-bf16, causal, split-K=2 ------------
// Work remap: wid = (x + 3*y) & 31 balances per-CU load. Softmax in log2
// domain (exp2f; scale folded in Q).
__global__ __launch_bounds__(256,3) void k_attn(
    const short* __restrict__ qh, const short* __restrict__ ql,
    const short* __restrict__ kh, const short* __restrict__ kl,
    const short* __restrict__ vth, const short* __restrict__ vtl,
    float* __restrict__ po, float* __restrict__ pm, float* __restrict__ pl){
  int wid = (blockIdx.x + 3*blockIdx.y) & 31;
  int qt = wid >> 1, half = wid & 1, bh = blockIdx.y;
  int q0 = qt * 64;
  long base = (long)bh * 1024 * 64;
  int ktb = half ? ((qt + 2) >> 1) : 0;
  int kte = half ? (qt + 1) : ((qt + 2) >> 1);
  __shared__ __align__(16) short skh[64*64], skl[64*64], svh[64*64], svl[64*64];
  __shared__ __align__(16) short sph[4][16*72], spl[4][16*72];
  int tid = threadIdx.x, w = tid >> 6, lane = tid & 63, l15 = lane & 15, quad = lane >> 4;
  bf16x8 qfh[2], qfl[2];
  #pragma unroll
  for (int c = 0; c < 2; c++){
    long qa = base + (long)(q0 + w*16 + l15)*64 + c*32 + quad*8;
    qfh[c] = *(const bf16x8*)(qh + qa);
    qfl[c] = *(const bf16x8*)(ql + qa);
  }
  f32x4 oacc[4];
  #pragma unroll
  for (int i = 0; i < 4; i++) oacc[i] = (f32x4){0.f,0.f,0.f,0.f};
  float m_i[4] = {-1e30f,-1e30f,-1e30f,-1e30f};
  float l_i[4] = {0.f,0.f,0.f,0.f};
  const short* gsrc = (w==0) ? kh : (w==1) ? kl : (w==2) ? vth : vtl;
  short* myb = (w==0) ? skh : (w==1) ? skl : (w==2) ? svh : svl;
  bool isv = (w >= 2);
  int rloc = lane >> 3, pch = lane & 7;
  for (int kt = ktb; kt < kte; kt++){
    #pragma unroll
    for (int j = 0; j < 8; j++){
      int r = j*8 + rloc;
      int c = pch ^ (r & 7);
      long ga = isv ? (base + (long)r*1024 + kt*64 + c*8)
                    : (base + (long)(kt*64 + r)*64 + c*8);
      gl_lds16(gsrc + ga, myb + j*512);
    }
    __syncthreads();
    f32x4 sfr[4];
    #pragma unroll
    for (int nt = 0; nt < 4; nt++){
      f32x4 c = (f32x4){0.f,0.f,0.f,0.f};
      int krow = (nt*16 + l15) * 64;
      #pragma unroll
      for (int ch = 0; ch < 2; ch++){
        int pc = ((ch*4 + quad) ^ (l15 & 7)) * 8;
        bf16x8 kfh = *(const bf16x8*)&skh[krow + pc];
        bf16x8 kfl = *(const bf16x8*)&skl[krow + pc];
        c = MFMA16(qfh[ch], kfh, c);
        c = MFMA16(qfh[ch], kfl, c);
        c = MFMA16(qfl[ch], kfh, c);
      }
      sfr[nt] = c;
    }
    if (kt == qt){
      #pragma unroll
      for (int nt = 0; nt < 4; nt++)
        #pragma unroll
        for (int rg = 0; rg < 4; rg++){
          int kp = nt*16 + l15, qp = w*16 + quad*4 + rg;
          if (kp > qp) sfr[nt][rg] = -1e30f;
        }
    }
    float rmax[4];
    #pragma unroll
    for (int rg = 0; rg < 4; rg++)
      rmax[rg] = fmaxf(fmaxf(sfr[0][rg], sfr[1][rg]), fmaxf(sfr[2][rg], sfr[3][rg]));
    #pragma unroll
    for (int xm = 1; xm < 16; xm <<= 1)
      #pragma unroll
      for (int rg = 0; rg < 4; rg++)
        rmax[rg] = fmaxf(rmax[rg], __shfl_xor(rmax[rg], xm, 64));
    float alpha[4];
    #pragma unroll
    for (int rg = 0; rg < 4; rg++){
      float mn = fmaxf(m_i[rg], rmax[rg]);
      alpha[rg] = exp2f(m_i[rg] - mn);
      m_i[rg] = mn;
    }
    float rsum[4] = {0.f,0.f,0.f,0.f};
    #pragma unroll
    for (int nt = 0; nt < 4; nt++)
      #pragma unroll
      for (int rg = 0; rg < 4; rg++){
        float p = exp2f(sfr[nt][rg] - m_i[rg]);
        sfr[nt][rg] = p; rsum[rg] += p;
      }
    #pragma unroll
    for (int xm = 1; xm < 16; xm <<= 1)
      #pragma unroll
      for (int rg = 0; rg < 4; rg++)
        rsum[rg] += __shfl_xor(rsum[rg], xm, 64);
    #pragma unroll
    for (int rg = 0; rg < 4; rg++) l_i[rg] = l_i[rg]*alpha[rg] + rsum[rg];
    #pragma unroll
    for (int hd = 0; hd < 4; hd++)
      #pragma unroll
      for (int rg = 0; rg < 4; rg++) oacc[hd][rg] *= alpha[rg];
    #pragma unroll
    for (int nt = 0; nt < 4; nt++)
      #pragma unroll
      for (int rg = 0; rg < 4; rg++){
        float p = sfr[nt][rg];
        short hv = f2bf(p);
        sph[w][(quad*4+rg)*72 + nt*16 + l15] = hv;
        spl[w][(quad*4+rg)*72 + nt*16 + l15] = f2bf(p - bf2f(hv));
      }
    bf16x8 pfh[2], pfl[2];
    #pragma unroll
    for (int ch = 0; ch < 2; ch++){
      pfh[ch] = *(const bf16x8*)&sph[w][l15*72 + ch*32 + quad*8];
      pfl[ch] = *(const bf16x8*)&spl[w][l15*72 + ch*32 + quad*8];
    }
    #pragma unroll
    for (int hd = 0; hd < 4; hd++){
      int vrow = (hd*16 + l15) * 64;
      #pragma unroll
      for (int ch = 0; ch < 2; ch++){
        int pc = ((ch*4 + quad) ^ (l15 & 7)) * 8;
        bf16x8 vfh = *(const bf16x8*)&svh[vrow + pc];
        bf16x8 vfl = *(const bf16x8*)&svl[vrow + pc];
        oacc[hd] = MFMA16(pfh[ch], vfh, oacc[hd]);
        oacc[hd] = MFMA16(pfh[ch], vfl, oacc[hd]);
        oacc[hd] = MFMA16(pfl[ch], vfh, oacc[hd]);
      }
    }
    __syncthreads();
  }
  long pb = ((long)(half*24 + bh)*1024);
  #pragma unroll
  for (int hdt = 0; hdt < 4; hdt++)
    #pragma unroll
    for (int rg = 0; rg < 4; rg++){
      int qp = q0 + w*16 + quad*4 + rg;
      po[(pb + qp)*64 + hdt*16 + l15] = oacc[hdt][rg];
    }
  if (l15 == 0){
    #pragma unroll
    for (int rg = 0; rg < 4; rg++){
      int qp = q0 + w*16 + quad*4 + rg;
      pm[pb + qp] = m_i[rg];
      pl[pb + qp] = l_i[rg];
    }
  }
}

// ---------------- attention combine: merge 2 partials -> bf16 hi/lo ---------
// log2-domain partials: weights via exp2f.
__global__ void k_attn_combine(const float* __restrict__ po, const float* __restrict__ pm,
                               const float* __restrict__ pl,
                               short* __restrict__ oh, short* __restrict__ ol){
  int bh = blockIdx.y, tid = threadIdx.x;
  int r = blockIdx.x*64 + (tid >> 2);
  int c0 = (tid & 3) * 16;
  long i0 = (long)bh*1024 + r;
  long i1 = (long)(24 + bh)*1024 + r;
  float m0 = pm[i0], m1 = pm[i1], l0 = pl[i0], l1 = pl[i1];
  float m = fmaxf(m0, m1);
  float a0 = exp2f(m0 - m), a1 = exp2f(m1 - m);
  float inv = 1.f / (a0*l0 + a1*l1);
  a0 *= inv; a1 *= inv;
  int b = bh / 12, hh = bh % 12;
  long ob = ((long)(b*1024 + r))*768 + hh*64 + c0;
  short hv[16], lv[16];
  #pragma unroll
  for (int j = 0; j < 4; j++){
    float4 o0 = *(const float4*)&po[i0*64 + c0 + j*4];
    float4 o1 = *(const float4*)&po[i1*64 + c0 + j*4];
    float vs[4] = {a0*o0.x + a1*o1.x, a0*o0.y + a1*o1.y,
                   a0*o0.z + a1*o1.z, a0*o0.w + a1*o1.w};
    #pragma unroll
    for (int q = 0; q < 4; q++){
      short h = f2bf(vs[q]);
      hv[j*4+q] = h; lv[j*4+q] = f2bf(vs[q] - bf2f(h));
    }
  }
  *(bf16x8*)(oh + ob)     = *(bf16x8*)&hv[0];
  *(bf16x8*)(oh + ob + 8) = *(bf16x8*)&hv[8];
  *(bf16x8*)(ol + ob)     = *(bf16x8*)&lv[0];
  *(bf16x8*)(ol + ob + 8) = *(bf16x8*)&lv[8];
}

// ---------------- split GEMM Wo -> partials, BM=64 BN=128, split-K=2 --------
// grid (32,6,2) = 384 blocks = 1.5/CU. Partials fp32; combine fused into
// k_ln2router.
__global__ __launch_bounds__(256,3) void k_wo(
    const short* __restrict__ Ah, const short* __restrict__ Al,
    const short* __restrict__ Bh, const short* __restrict__ Bl,
    float* __restrict__ p0, float* __restrict__ p1){
  int M0 = blockIdx.x * 64, N0 = blockIdx.y * 128;
  int ks = blockIdx.z;
  int kbeg = ks * 384;
  float* wp = ks ? p1 : p0;
  __shared__ __align__(16) short lah[64*64], lal[64*64], lbh[128*64], lbl[128*64];
  int tid = threadIdx.x;
  int w = tid >> 6, lane = tid & 63, l15 = lane & 15, quad = lane >> 4;
  int mbase = (w & 1) * 32, nbase = (w >> 1) * 64;
  f32x4 acc[2][4];
  #pragma unroll
  for (int i = 0; i < 2; i++)
    #pragma unroll
    for (int j = 0; j < 4; j++) acc[i][j] = (f32x4){0.f,0.f,0.f,0.f};
  int rl = lane >> 3, pch = lane & 7;
  long gA[2], gB[4];
  #pragma unroll
  for (int j = 0; j < 2; j++){
    int r = w*16 + j*8 + rl;
    int c = pch ^ (r & 7);
    gA[j] = (long)(M0 + r)*768 + kbeg + c*8;
  }
  #pragma unroll
  for (int j = 0; j < 4; j++){
    int r = w*32 + j*8 + rl;
    int c = pch ^ (r & 7);
    gB[j] = (long)(N0 + r)*768 + kbeg + c*8;
  }
  for (int k0 = 0; k0 < 384; k0 += 64){
    #pragma unroll
    for (int j = 0; j < 2; j++){
      gl_lds16(Ah + gA[j] + k0, lah + w*1024 + j*512);
      gl_lds16(Al + gA[j] + k0, lal + w*1024 + j*512);
    }
    #pragma unroll
    for (int j = 0; j < 4; j++){
      gl_lds16(Bh + gB[j] + k0, lbh + w*2048 + j*512);
      gl_lds16(Bl + gB[j] + k0, lbl + w*2048 + j*512);
    }
    __syncthreads();
    #pragma unroll
    for (int kk = 0; kk < 2; kk++){
      int swq = ((kk*4 + quad) ^ (l15 & 7)) * 8;
      bf16x8 afh[2], afl[2];
      #pragma unroll
      for (int mt = 0; mt < 2; mt++){
        afh[mt] = *(const bf16x8*)&lah[(mbase+mt*16+l15)*64 + swq];
        afl[mt] = *(const bf16x8*)&lal[(mbase+mt*16+l15)*64 + swq];
      }
      #pragma unroll
      for (int nt = 0; nt < 4; nt++){
        bf16x8 bfh = *(const bf16x8*)&lbh[(nbase+nt*16+l15)*64 + swq];
        bf16x8 bfl = *(const bf16x8*)&lbl[(nbase+nt*16+l15)*64 + swq];
        #pragma unroll
        for (int mt = 0; mt < 2; mt++){
          acc[mt][nt] = MFMA16(afh[mt], bfh, acc[mt][nt]);
          acc[mt][nt] = MFMA16(afh[mt], bfl, acc[mt][nt]);
          acc[mt][nt] = MFMA16(afl[mt], bfh, acc[mt][nt]);
        }
      }
    }
    __syncthreads();
  }
  #pragma unroll
  for (int mt = 0; mt < 2; mt++)
    #pragma unroll
    for (int nt = 0; nt < 4; nt++)
      #pragma unroll
      for (int rg = 0; rg < 4; rg++){
        int m = M0 + mbase + mt*16 + quad*4 + rg;
        int n = N0 + nbase + nt*16 + l15;
        wp[(long)m*768 + n] = acc[mt][nt][rg];
      }
}

// ---------------- fused: h = P0+P1+x+bo; LN2; router (no global atomics) ----
// grid 256 x 256thr; wave wv handles tokens wv*2, wv*2+1. Vectorized float4.
__global__ void k_ln2router(const float* __restrict__ p0, const float* __restrict__ p1,
                            const float* __restrict__ x, const float* __restrict__ bo,
                            const float* __restrict__ g, const float* __restrict__ bb,
                            const float* __restrict__ Wr, const float* __restrict__ br,
                            float* __restrict__ hout, short* __restrict__ xn2,
                            int* __restrict__ sel, float* __restrict__ gw){
  int wv = (blockIdx.x*256 + threadIdx.x) >> 6;
  int lane = threadIdx.x & 63;
  #pragma unroll
  for (int rep = 0; rep < 2; rep++){
    int t = wv*2 + rep;
    float4 hv[3];
    #pragma unroll
    for (int j = 0; j < 3; j++){
      long i = (long)t*192 + j*64 + lane;
      float4 a  = ((const float4*)p0)[i];
      float4 b  = ((const float4*)p1)[i];
      float4 xx = ((const float4*)x)[i];
      float4 bv = ((const float4*)bo)[j*64 + lane];
      float4 h;
      h.x = a.x + b.x + xx.x + bv.x;
      h.y = a.y + b.y + xx.y + bv.y;
      h.z = a.z + b.z + xx.z + bv.z;
      h.w = a.w + b.w + xx.w + bv.w;
      ((float4*)hout)[i] = h;
      hv[j] = h;
    }
    float s = 0.f, q = 0.f;
    #pragma unroll
    for (int j = 0; j < 3; j++){
      s += hv[j].x + hv[j].y + hv[j].z + hv[j].w;
      q += hv[j].x*hv[j].x + hv[j].y*hv[j].y + hv[j].z*hv[j].z + hv[j].w*hv[j].w;
    }
    #pragma unroll
    for (int xm = 1; xm < 64; xm <<= 1){ s += __shfl_xor(s, xm, 64); q += __shfl_xor(q, xm, 64); }
    float mean = s * (1.f/768.f);
    float var  = q * (1.f/768.f) - mean*mean;
    float inv  = 1.f / sqrtf(var + 1e-5f);
    float part[8] = {0,0,0,0,0,0,0,0};
    #pragma unroll
    for (int j = 0; j < 3; j++){
      int d0 = (j*64 + lane) * 4;
      float4 gv = ((const float4*)g)[j*64 + lane];
      float4 bbv = ((const float4*)bb)[j*64 + lane];
      float xn0 = (hv[j].x - mean)*inv*gv.x + bbv.x;
      float xn1 = (hv[j].y - mean)*inv*gv.y + bbv.y;
      float xn2v = (hv[j].z - mean)*inv*gv.z + bbv.z;
      float xn3 = (hv[j].w - mean)*inv*gv.w + bbv.w;
      bf16x4 pk = (bf16x4){f2bf(xn0), f2bf(xn1), f2bf(xn2v), f2bf(xn3)};
      *(bf16x4*)&xn2[(long)t*768 + d0] = pk;
      #pragma unroll
      for (int e = 0; e < 8; e++){
        part[e] += xn0 * Wr[(d0+0)*8 + e];
        part[e] += xn1 * Wr[(d0+1)*8 + e];
        part[e] += xn2v * Wr[(d0+2)*8 + e];
        part[e] += xn3 * Wr[(d0+3)*8 + e];
      }
    }
    #pragma unroll
    for (int xm = 1; xm < 64; xm <<= 1)
      #pragma unroll
      for (int e = 0; e < 8; e++) part[e] += __shfl_xor(part[e], xm, 64);
    if (lane == 0){
      float lg[8];
      #pragma unroll
      for (int e = 0; e < 8; e++) lg[e] = part[e] + br[e];
      int i1 = 0;
      for (int e = 1; e < 8; e++) if (lg[e] > lg[i1]) i1 = e;
      int i2 = -1;
      for (int e = 0; e < 8; e++){ if (e == i1) continue; if (i2 < 0 || lg[e] > lg[i2]) i2 = e; }
      float e2 = expf(lg[i2] - lg[i1]);
      float is = 1.f / (1.f + e2);
      gw[t*2]   = is;
      gw[t*2+1] = e2 * is;
      sel[t*2]   = i1;
      sel[t*2+1] = i2;
    }
  }
}

// single-block compaction: wave-aggregated ballot histogram + placement.
__global__ void k_build(const int* __restrict__ sel, int* __restrict__ poffs,
                        int* __restrict__ mbc, int* __restrict__ ptot,
                        int* __restrict__ pperm, int* __restrict__ inv){
  __shared__ int cnt8[8], cur[8], wbase[16][8];
  int tid = threadIdx.x;   // 1024
  int lane = tid & 63, wv = tid >> 6;
  if (tid < 8) cnt8[tid] = 0;
  __syncthreads();
  int sv[4];
  #pragma unroll
  for (int r = 0; r < 4; r++){
    sv[r] = sel[tid + r*1024];
    #pragma unroll
    for (int e = 0; e < 8; e++){
      unsigned long long mk = __ballot(sv[r] == e);
      if (lane == 0) atomicAdd(&cnt8[e], (int)__popcll(mk));
    }
  }
  __syncthreads();
  if (tid == 0){
    int p = 0;
    for (int e = 0; e < 8; e++){
      cur[e] = p; poffs[e] = p;
      int pc = (cnt8[e] + 127) & ~127;
      mbc[e] = pc >> 7;
      p += pc;
    }
    *ptot = p;
  }
  __syncthreads();
  #pragma unroll
  for (int r = 0; r < 5; r++) pperm[tid + r*1024] = -1;
  __syncthreads();
  unsigned long long lmask = (1ull << lane) - 1ull;
  #pragma unroll
  for (int r = 0; r < 4; r++){
    int s = sv[r];
    unsigned long long mk[8];
    #pragma unroll
    for (int e = 0; e < 8; e++) mk[e] = __ballot(s == e);
    if (lane == 0){
      #pragma unroll
      for (int e = 0; e < 8; e++)
        wbase[wv][e] = atomicAdd(&cur[e], (int)__popcll(mk[e]));
    }
    unsigned long long mks = 0;
    #pragma unroll
    for (int e = 0; e < 8; e++) if (s == e) mks = mk[e];   // static indexing (rule #20)
    int pos = wbase[wv][s] + (int)__popcll(mks & lmask);
    int i = tid + r*1024;
    pperm[pos] = i;
    inv[i] = pos;
  }
}

// ---------------- MoE GEMM1: h1[p] = gelu(xn2[tok(p)] @ W1T[e] + b1) --------
// grid (192 = e*24+n weight-tile [XCD-pinned], 16 = Mblk-within-expert)
// Round-1 proven config: single-buffer, 2 barriers/K-step, 3 blocks/CU.
__global__ __launch_bounds__(256,3) void k_moe1(
    const short* __restrict__ xn2, const short* __restrict__ W1T,
    const float* __restrict__ b1,
    const int* __restrict__ poffs, const int* __restrict__ mbc,
    const int* __restrict__ pperm, short* __restrict__ h1){
  int t = blockIdx.x;
  int e = t / 24, n = t % 24;
  if ((int)blockIdx.y >= mbc[e]) return;
  int M0 = poffs[e] + blockIdx.y * 128;
  int N0 = n * 128;
  const short* Bp = W1T + (long)e * 3072 * 768;
  __shared__ __align__(16) short la[128*64], lb[128*64];
  __shared__ int rtok[128];
  int tid = threadIdx.x, w = tid >> 6, lane = tid & 63, l15 = lane & 15, quad = lane >> 4;
  if (tid < 128) rtok[tid] = pperm[M0 + tid];
  __syncthreads();
  int rl = lane >> 3, pch = lane & 7;
  long gA[4], gB[4];
  #pragma unroll
  for (int j = 0; j < 4; j++){
    int r = w*32 + j*8 + rl;
    int c = pch ^ (r & 7);
    int tk = rtok[r]; tk = (tk >= 0) ? (tk >> 1) : 0;
    gA[j] = (long)tk*768 + c*8;
    gB[j] = (long)(N0 + r)*768 + c*8;
  }
  short* ldA = la + w*2048;
  short* ldB = lb + w*2048;
  f32x4 acc[4][4];
  #pragma unroll
  for (int i = 0; i < 4; i++)
    #pragma unroll
    for (int j = 0; j < 4; j++) acc[i][j] = (f32x4){0.f,0.f,0.f,0.f};
  int mbase = (w & 1) * 64, nbase = (w >> 1) * 64;
  for (int k0 = 0; k0 < 768; k0 += 64){
    #pragma unroll
    for (int j = 0; j < 4; j++) gl_lds16(xn2 + gA[j] + k0, ldA + j*512);
    #pragma unroll
    for (int j = 0; j < 4; j++) gl_lds16(Bp  + gB[j] + k0, ldB + j*512);
    __syncthreads();
    #pragma unroll
    for (int kk = 0; kk < 2; kk++){
      int swq = ((kk*4 + quad) ^ (l15 & 7)) * 8;
      bf16x8 af[4];
      #pragma unroll
      for (int mt = 0; mt < 4; mt++)
        af[mt] = *(const bf16x8*)&la[(mbase+mt*16+l15)*64 + swq];
      #pragma unroll
      for (int nt = 0; nt < 4; nt++){
        bf16x8 bf = *(const bf16x8*)&lb[(nbase+nt*16+l15)*64 + swq];
        #pragma unroll
        for (int mt = 0; mt < 4; mt++) acc[mt][nt] = MFMA16(af[mt], bf, acc[mt][nt]);
      }
    }
    __syncthreads();
  }
  #pragma unroll
  for (int mt = 0; mt < 4; mt++)
    #pragma unroll
    for (int nt = 0; nt < 4; nt++)
      #pragma unroll
      for (int rg = 0; rg < 4; rg++){
        int ml = mbase + mt*16 + quad*4 + rg;
        if (rtok[ml] >= 0){
          int nn = N0 + nbase + nt*16 + l15;
          float vv = acc[mt][nt][rg] + b1[e*3072 + nn];
          float gl = 0.5f * vv * (1.f + erff(vv * 0.70710678118654752f));
          h1[(long)(M0 + ml)*3072 + nn] = f2bf(gl);
        }
      }
}

// ---------------- MoE GEMM2: E[ks][slot] = h1 @ W2T[e](+b2), split-K=4 ------
// grid (192 = e*24 + n*4 + ks weight-tile, 16 = Mblk-within-expert)
// Round-1 proven config.
__global__ __launch_bounds__(256,4) void k_moe2(
    const short* __restrict__ h1, const short* __restrict__ W2T,
    const float* __restrict__ b2,
    const int* __restrict__ poffs, const int* __restrict__ mbc,
    float* __restrict__ e0, float* __restrict__ e1,
    float* __restrict__ e2, float* __restrict__ e3){
  int t = blockIdx.x;
  int e = t / 24, r24 = t % 24;
  int n = r24 >> 2, ks = r24 & 3;
  if ((int)blockIdx.y >= mbc[e]) return;
  int M0 = poffs[e] + blockIdx.y * 128;
  int N0 = n * 128;
  int kbeg = ks * 768;
  const short* Bp = W2T + (long)e * 768 * 3072;
  float* eo = (ks == 0) ? e0 : (ks == 1) ? e1 : (ks == 2) ? e2 : e3;
  __shared__ __align__(16) short la[128*64], lb[128*64];
  int tid = threadIdx.x, w = tid >> 6, lane = tid & 63, l15 = lane & 15, quad = lane >> 4;
  int rl = lane >> 3, pch = lane & 7;
  long gA[4], gB[4];
  #pragma unroll
  for (int j = 0; j < 4; j++){
    int r = w*32 + j*8 + rl;
    int c = pch ^ (r & 7);
    gA[j] = (long)(M0 + r)*3072 + kbeg + c*8;
    gB[j] = (long)(N0 + r)*3072 + kbeg + c*8;
  }
  short* ldA = la + w*2048;
  short* ldB = lb + w*2048;
  f32x4 acc[4][4];
  #pragma unroll
  for (int i = 0; i < 4; i++)
    #pragma unroll
    for (int j = 0; j < 4; j++) acc[i][j] = (f32x4){0.f,0.f,0.f,0.f};
  int mbase = (w & 1) * 64, nbase = (w >> 1) * 64;
  for (int k0 = 0; k0 < 768; k0 += 64){
    #pragma unroll
    for (int j = 0; j < 4; j++) gl_lds16(h1 + gA[j] + k0, ldA + j*512);
    #pragma unroll
    for (int j = 0; j < 4; j++) gl_lds16(Bp + gB[j] + k0, ldB + j*512);
    __syncthreads();
    #pragma unroll
    for (int kk = 0; kk < 2; kk++){
      int swq = ((kk*4 + quad) ^ (l15 & 7)) * 8;
      bf16x8 af[4];
      #pragma unroll
      for (int mt = 0; mt < 4; mt++)
        af[mt] = *(const bf16x8*)&la[(mbase+mt*16+l15)*64 + swq];
      #pragma unroll
      for (int nt = 0; nt < 4; nt++){
        bf16x8 bf = *(const bf16x8*)&lb[(nbase+nt*16+l15)*64 + swq];
        #pragma unroll
        for (int mt = 0; mt < 4; mt++) acc[mt][nt] = MFMA16(af[mt], bf, acc[mt][nt]);
      }
    }
    __syncthreads();
  }
  #pragma unroll
  for (int mt = 0; mt < 4; mt++)
    #pragma unroll
    for (int nt = 0; nt < 4; nt++)
      #pragma unroll
      for (int rg = 0; rg < 4; rg++){
        int ml = mbase + mt*16 + quad*4 + rg;
        int nn = N0 + nbase + nt*16 + l15;
        float vv = acc[mt][nt][rg] + ((ks == 0) ? b2[e*768 + nn] : 0.f);
        eo[(long)(M0 + ml)*768 + nn] = vv;
      }
}

// ---------------- final combine: out = h + Σ_slot g*(E0+E1+E2+E3)[slot] -----
__global__ void k_combine(const float* __restrict__ h,
                          const float* __restrict__ e0, const float* __restrict__ e1,
                          const float* __restrict__ e2, const float* __restrict__ e3,
                          const int* __restrict__ inv, const float* __restrict__ gw,
                          float* __restrict__ out){
  int i = blockIdx.x * 256 + threadIdx.x;     // 393216 float4s
  int t = i / 192, c = i - t * 192;
  int s0 = inv[2*t], s1 = inv[2*t+1];
  float g0 = gw[2*t], g1 = gw[2*t+1];
  float4 a  = ((const float4*)h)[i];
  long o0 = (long)s0*192 + c, o1 = (long)s1*192 + c;
  float4 x0 = ((const float4*)e0)[o0];
  float4 y0 = ((const float4*)e1)[o0];
  float4 z0 = ((const float4*)e2)[o0];
  float4 w0 = ((const float4*)e3)[o0];
  float4 x1 = ((const float4*)e0)[o1];
  float4 y1 = ((const float4*)e1)[o1];
  float4 z1 = ((const float4*)e2)[o1];
  float4 w1 = ((const float4*)e3)[o1];
  float4 o;
  o.x = a.x + g0*(x0.x + y0.x + z0.x + w0.x) + g1*(x1.x + y1.x + z1.x + w1.x);
  o.y = a.y + g0*(x0.y + y0.y + z0.y + w0.y) + g1*(x1.y + y1.y + z1.y + w1.y);
  o.z = a.z + g0*(x0.z + y0.z + z0.z + w0.z) + g1*(x1.z + y1.z + z1.z + w1.z);
  o.w = a.w + g0*(x0.w + y0.w + z0.w + w0.w) + g1*(x1.w + y1.w + z1.w + w1.w);
  ((float4*)out)[i] = o;
}

// ---------------- launcher ----------------
extern "C" void kernel_launch(void* const* d_in, const int* in_sizes, int n_in,
                              void* d_out, int out_size, void* d_ws, size_t ws_size,
                              hipStream_t stream){
  const float* x    = (const float*)d_in[0];
  const float* ln1g = (const float*)d_in[1];
  const float* ln1b = (const float*)d_in[2];
  const float* Wq   = (const float*)d_in[3];
  const float* Wk   = (const float*)d_in[4];
  const float* Wv   = (const float*)d_in[5];
  const float* Wo   = (const float*)d_in[6];
  const float* bo   = (const float*)d_in[7];
  const float* ln2g = (const float*)d_in[8];
  const float* ln2b = (const float*)d_in[9];
  const float* Wr   = (const float*)d_in[10];
  const float* br   = (const float*)d_in[11];
  const float* W1   = (const float*)d_in[12];
  const float* b1   = (const float*)d_in[13];
  const float* W2   = (const float*)d_in[14];
  const float* b2   = (const float*)d_in[15];

  char* ws = (char*)d_ws;
  size_t off = 0;
  auto alloc = [&](size_t bytes) -> void* {
    void* p = ws + off;
    off += (bytes + 255) & ~(size_t)255;
    return p;
  };
  short* WQKVH = (short*)alloc(2304l*768*2);
  short* WQKVL = (short*)alloc(2304l*768*2);
  short* WOH   = (short*)alloc(768l*768*2);
  short* WOL   = (short*)alloc(768l*768*2);
  short* W1T   = (short*)alloc(8l*3072*768*2);
  short* W2T   = (short*)alloc(8l*768*3072*2);
  short* XN1H  = (short*)alloc(2048l*768*2);
  short* XN1L  = (short*)alloc(2048l*768*2);
  short* QH    = (short*)alloc(2048l*768*2);
  short* QL    = (short*)alloc(2048l*768*2);
  short* KH    = (short*)alloc(2048l*768*2);
  short* KL    = (short*)alloc(2048l*768*2);
  short* VTH   = (short*)alloc(2048l*768*2);
  short* VTL   = (short*)alloc(2048l*768*2);
  short* ATH   = (short*)alloc(2048l*768*2);
  short* ATL   = (short*)alloc(2048l*768*2);
  float* HBUF  = (float*)alloc(2048l*768*4);
  short* XN2   = (short*)alloc(2048l*768*2);
  short* H1    = (short*)alloc(5120l*3072*2);
  float* E0    = (float*)alloc(5120l*768*4);
  float* E1    = (float*)alloc(5120l*768*4);
  float* PO    = (float*)alloc(2l*24*1024*64*4);
  float* PM    = (float*)alloc(2l*24*1024*4);
  float* PL    = (float*)alloc(2l*24*1024*4);
  int*   POFF  = (int*)alloc(8*4);
  int*   MBC   = (int*)alloc(8*4);
  int*   PTOT  = (int*)alloc(4);
  int*   SEL   = (int*)alloc(4096*4);
  int*   PPERM = (int*)alloc(5120*4);
  int*   INV   = (int*)alloc(4096*4);
  float* GW    = (float*)alloc(4096*4);
  (void)ws_size; (void)in_sizes; (void)n_in; (void)out_size;

  // E2/E3: alias the attention-path buffers (XN1H..ATL = 10 x 3,145,728 B
  // = exactly 2 x 5120*768*4 B). All consumers of that region (k_qkv,
  // k_attn, k_wo) complete before k_moe2 runs on the same stream.
  float* E2 = (float*)XN1H;
  float* E3 = E2 + 5120l*768;
  // WP0/WP1: alias PO (12.58 MB = exactly 2 x 2048*768*4). k_attn_combine
  // (PO's last consumer) completes before k_wo writes on the same stream.
  float* WP0 = PO;
  float* WP1 = PO + 2048l*768;

  // fused weight prep + LN1: ONE launch (saves 3 launches + co-schedules the
  // small prep work under the big W1/W2 transposes)
  k_prep<<<11840,256,0,stream>>>(
      Wq, Wk, Wv, Wo, WQKVH, WQKVL, WOH, WOL,
      W1, W1T, W2, W2T,
      x, ln1g, ln1b, XN1H, XN1L);

  // attention path (split-bf16 precision)
  k_qkv<<<dim3(32,18),256,0,stream>>>(XN1H, XN1L, WQKVH, WQKVL, QH, QL, KH, KL, VTH, VTL);
  k_attn<<<dim3(32,24),256,0,stream>>>(QH, QL, KH, KL, VTH, VTL, PO, PM, PL);
  k_attn_combine<<<dim3(16,24),256,0,stream>>>(PO, PM, PL, ATH, ATL);
  k_wo<<<dim3(32,6,2),256,0,stream>>>(ATH, ATL, WOH, WOL, WP0, WP1);

  // fused residual+LN2+router, then MoE (no global atomics)
  k_ln2router<<<256,256,0,stream>>>(WP0, WP1, x, bo, ln2g, ln2b, Wr, br,
                                    HBUF, XN2, SEL, GW);
  k_build<<<1,1024,0,stream>>>(SEL, POFF, MBC, PTOT, PPERM, INV);
  k_moe1<<<dim3(192,16),256,0,stream>>>(XN2, W1T, b1, POFF, MBC, PPERM, H1);
  k_moe2<<<dim3(192,16),256,0,stream>>>(H1, W2T, b2, POFF, MBC, E0, E1, E2, E3);
  k_combine<<<1536,256,0,stream>>>(HBUF, E0, E1, E2, E3, INV, GW, (float*)d_out);
}